// Round 2
// baseline (1095.270 us; speedup 1.0000x reference)
//
#include <hip/hip_runtime.h>
#include <hip/hip_bf16.h>

typedef __hip_bfloat16 bf16;
typedef short short8 __attribute__((ext_vector_type(8)));
typedef short short4v __attribute__((ext_vector_type(4)));
typedef float floatx4 __attribute__((ext_vector_type(4)));
typedef int intx4 __attribute__((ext_vector_type(4)));
typedef unsigned int uintx4 __attribute__((ext_vector_type(4)));

#define B_ 4
#define SD_ 2048
#define SE_ 2048
#define DM_ 1024
#define H_ 8
#define DFF_ 4096

__device__ __forceinline__ float b2f(bf16 v) { return __bfloat162float(v); }
__device__ __forceinline__ bf16 f2b(float v) { return __float2bfloat16(v); }
__device__ __forceinline__ short f2s(float v) { return __builtin_bit_cast(short, __float2bfloat16(v)); }

// pack two f32 -> one u32 of 2x bf16 (lo = first arg)
__device__ __forceinline__ unsigned cvtpk_bf16(float lo, float hi) {
    unsigned r;
    asm("v_cvt_pk_bf16_f32 %0, %1, %2" : "=v"(r) : "v"(lo), "v"(hi));
    return r;
}
// x' = [x_lo32, y_lo32], y' = [x_hi32, y_hi32]
__device__ __forceinline__ void pl32swap(unsigned &x, unsigned &y) {
    asm("v_permlane32_swap_b32 %0, %1" : "+v"(x), "+v"(y));
}
// x' = [x_g0, y_g0, x_g2, y_g2], y' = [x_g1, y_g1, x_g3, y_g3] (16-lane groups)
__device__ __forceinline__ void pl16swap(unsigned &x, unsigned &y) {
    asm("v_permlane16_swap_b32 %0, %1" : "+v"(x), "+v"(y));
}

// async global->LDS, 16B/lane. LDS dest = wave-uniform base + lane*16.
__device__ __forceinline__ void gl_lds16(const short* g, short* l) {
    __builtin_amdgcn_global_load_lds(
        (const __attribute__((address_space(1))) void*)g,
        (__attribute__((address_space(3))) void*)l, 16, 0, 0);
}

// ---------------------------------------------------------------------------
__global__ __launch_bounds__(256) void cvt_f32_bf16(
    const float* __restrict__ in, bf16* __restrict__ out, int n)
{
    int i = (blockIdx.x * 256 + threadIdx.x) * 8;
    if (i >= n) return;
    floatx4 a = *(const floatx4*)(in + i);
    floatx4 b = *(const floatx4*)(in + i + 4);
    short8 r;
#pragma unroll
    for (int k = 0; k < 4; ++k) { r[k] = f2s(a[k]); r[k + 4] = f2s(b[k]); }
    *(short8*)(out + i) = r;
}

// fp32 [1024,1024] -> bf16 transposed
__global__ __launch_bounds__(256) void cvt_f32_bf16_T(
    const float* __restrict__ in, bf16* __restrict__ out)
{
    __shared__ short tl[32][36];
    const int tid = threadIdx.x;
    const int i = tid >> 3;
    const int j = (tid & 7) * 4;
    const int r0 = blockIdx.x * 32, c0 = blockIdx.y * 32;
    floatx4 v = *(const floatx4*)(in + (size_t)(r0 + i) * 1024 + c0 + j);
#pragma unroll
    for (int p = 0; p < 4; ++p) tl[i][j + p] = f2s(v[p]);
    __syncthreads();
    short4v r;
#pragma unroll
    for (int p = 0; p < 4; ++p) r[p] = tl[j + p][i];
    *(short4v*)(out + (size_t)(c0 + i) * 1024 + r0 + j) = r;
}

// composed bias: out[o] = sum_m w[o,m]*bin[m] + badd[o]
__global__ __launch_bounds__(256) void bias_comp(
    const float* __restrict__ w, const float* __restrict__ bin,
    const float* __restrict__ badd, float* __restrict__ out)
{
    __shared__ float red[4];
    const int o = blockIdx.x;
    const int t = threadIdx.x;
    float s = 0.f;
#pragma unroll
    for (int i = t; i < 1024; i += 256) s += w[(size_t)o * 1024 + i] * bin[i];
#pragma unroll
    for (int off = 32; off >= 1; off >>= 1) s += __shfl_xor(s, off);
    if ((t & 63) == 0) red[t >> 6] = s;
    __syncthreads();
    if (t == 0) out[o] = red[0] + red[1] + red[2] + red[3] + badd[o];
}

// ---------------------------------------------------------------------------
// GEMM: C = act(A @ W^T + bias).  global_load_lds staging with XOR swizzle:
// block j of row r stored at position j^(r&7) -> fragment b128 reads spread
// over all 8 bank windows (2 lanes each = free), no padding needed.
// ---------------------------------------------------------------------------
template <int RELU>
__global__ __launch_bounds__(256) void gemm_bt(
    const bf16* __restrict__ A, const bf16* __restrict__ W,
    const float* __restrict__ bias, bf16* __restrict__ C,
    int M, int N, int K)
{
    __shared__ __align__(16) short As[16 * 512];
    __shared__ __align__(16) short Ws[16 * 512];

    const int tid  = threadIdx.x;
    const int lane = tid & 63;
    const int wave = tid >> 6;
    const int quad = lane >> 4;
    const int l16  = lane & 15;
    const int r7   = l16 & 7;
    const int bm0  = blockIdx.y * 128;
    const int bn0  = blockIdx.x * 128;
    const int wm   = (wave >> 1) * 64;
    const int wn   = (wave & 1) * 64;

    const int scol = (((lane & 7) ^ (lane >> 3)) * 8);
    const short* Ag = (const short*)A + (size_t)(bm0 + wave * 32 + (lane >> 3)) * K + scol;
    const short* Wg = (const short*)W + (size_t)(bn0 + wave * 32 + (lane >> 3)) * K + scol;
    short* Al = As + (wave * 4) * 512;
    short* Wl = Ws + (wave * 4) * 512;

    floatx4 acc[4][4];
#pragma unroll
    for (int i = 0; i < 4; ++i)
#pragma unroll
        for (int j = 0; j < 4; ++j)
            acc[i][j] = (floatx4){0.f, 0.f, 0.f, 0.f};

    for (int k0 = 0; k0 < K; k0 += 64) {
        __syncthreads();
#pragma unroll
        for (int s = 0; s < 4; ++s) {
            gl_lds16(Ag + k0 + (size_t)s * 8 * K, Al + s * 512);
            gl_lds16(Wg + k0 + (size_t)s * 8 * K, Wl + s * 512);
        }
        __syncthreads();
#pragma unroll
        for (int kk = 0; kk < 64; kk += 32) {
            short8 af[4], bg[4];
#pragma unroll
            for (int i = 0; i < 4; ++i) {
                int row = wm + i * 16 + l16;          // row&7 == r7
                af[i] = *(const short8*)&As[(row >> 3) * 512 + r7 * 64 +
                                            (((quad + (kk >> 3)) ^ r7) << 3)];
            }
#pragma unroll
            for (int j = 0; j < 4; ++j) {
                int row = wn + j * 16 + l16;
                bg[j] = *(const short8*)&Ws[(row >> 3) * 512 + r7 * 64 +
                                            (((quad + (kk >> 3)) ^ r7) << 3)];
            }
#pragma unroll
            for (int i = 0; i < 4; ++i)
#pragma unroll
                for (int j = 0; j < 4; ++j)
                    acc[i][j] = __builtin_amdgcn_mfma_f32_16x16x32_bf16(
                        af[i], bg[j], acc[i][j], 0, 0, 0);
        }
    }

#pragma unroll
    for (int j = 0; j < 4; ++j) {
        int col = bn0 + wn + j * 16 + l16;
        float bv = bias ? bias[col] : 0.f;
#pragma unroll
        for (int i = 0; i < 4; ++i) {
            int row0 = bm0 + wm + i * 16 + quad * 4;
#pragma unroll
            for (int r = 0; r < 4; ++r) {
                float v = acc[i][j][r] + bv;
                if (RELU) v = fmaxf(v, 0.f);
                C[(size_t)(row0 + r) * N + col] = f2b(v);
            }
        }
    }
}

// ---------------------------------------------------------------------------
// V transpose: in rows [B*S, str] (head h at col h*128) -> out [B*H][128][S]
// ---------------------------------------------------------------------------
__global__ __launch_bounds__(256) void vtrans(
    const bf16* __restrict__ in, int str, bf16* __restrict__ out, int S)
{
    __shared__ short t[32][36];
    const int tid = threadIdx.x;
    const int s0  = blockIdx.x * 32;
    const int d0  = blockIdx.y * 32;
    const int bh  = blockIdx.z;
    const int b = bh >> 3, h = bh & 7;
    const int i = tid >> 3;
    const int j = (tid & 7) * 4;

    *(short4v*)&t[i][j] =
        *(const short4v*)(in + (size_t)(b * S + s0 + i) * str + h * 128 + d0 + j);
    __syncthreads();
    short4v r;
#pragma unroll
    for (int p = 0; p < 4; ++p) r[p] = t[j + p][i];
    *(short4v*)(out + ((size_t)bh * 128 + d0 + i) * S + s0 + j) = r;
}

// ---------------------------------------------------------------------------
// Flash attention v7: operand-swapped QK^T (S^T = K Q^T) so each lane holds
// P for one q-column (q = l16); P->A-frag transpose is done fully in-register
// via v_cvt_pk_bf16_f32 + permlane32/16_swap (no Ps LDS round-trip, no scalar
// ds_writes).  Unnormalized O + row-sums, K-split x2, gl_lds staging with
// XOR bank swizzle.
// ---------------------------------------------------------------------------
template <int CAUSAL>
__global__ __launch_bounds__(256) void flash_attn(
    const bf16* __restrict__ Q, int qstr, const bf16* __restrict__ K, int kstr,
    const bf16* __restrict__ Vt, const int* __restrict__ pad,
    bf16* __restrict__ Of, float* __restrict__ Ls, int Sq, int Sk)
{
    __shared__ __align__(16) short Ks[64 * 128];   // 16 KB, swizzled
    __shared__ __align__(16) short Vs[128 * 64];   // 16 KB, swizzled

    const int tid  = threadIdx.x;
    const int lane = tid & 63;
    const int wave = tid >> 6;
    const int quad = lane >> 4;
    const int l16  = lane & 15;
    const int r7   = l16 & 7;
    const int bh   = blockIdx.y;
    const int b    = bh >> 3;
    const int h    = bh & 7;
    const int par  = blockIdx.z;
    int tile = blockIdx.x;
    if (CAUSAL) tile = (tile & 1) ? (gridDim.x - 1 - (tile >> 1)) : (tile >> 1);
    const int q0 = tile * 128;
    const int qw = q0 + wave * 32;

    // Q fragments (row = l16, k = c*32 + quad*8 + j) -- used as B operand now
    short8 qf[2][4];
#pragma unroll
    for (int mi = 0; mi < 2; ++mi) {
        const bf16* qb = Q + (size_t)(b * Sq + qw + mi * 16 + l16) * qstr + h * 128;
#pragma unroll
        for (int c = 0; c < 4; ++c)
            qf[mi][c] = *(const short8*)(qb + c * 32 + quad * 8);
    }

    floatx4 o[2][8];
#pragma unroll
    for (int mi = 0; mi < 2; ++mi)
#pragma unroll
        for (int nf = 0; nf < 8; ++nf) o[mi][nf] = (floatx4){0.f, 0.f, 0.f, 0.f};
    float lsum[2] = {0.f, 0.f};

    const float sc = 0.08838834764831845f * 1.4426950408889634f;  // log2 scale
    int kEnd = Sk;
    if (CAUSAL && q0 + 128 < Sk) kEnd = q0 + 128;

    const bf16* vb0 = Vt + (size_t)bh * 128 * Sk;

    for (int ci = par; ci * 64 < kEnd; ci += 2) {
        const int kc = ci * 64;
        __syncthreads();
        // stage K[64 rows x 128] and V[128 rows x 64], XOR-swizzled blocks
#pragma unroll
        for (int s = 0; s < 4; ++s) {
            int seg = wave * 4 + s;
            int kr = seg * 4 + (lane >> 4);                 // 0..63
            int kg = (lane & 15) ^ (kr & 7);
            gl_lds16((const short*)K + (size_t)(b * Sk + kc + kr) * kstr + h * 128 + kg * 8,
                     Ks + seg * 512);
            int vr = seg * 8 + (lane >> 3);                 // 0..127
            int vg = (lane & 7) ^ (vr & 7);
            gl_lds16((const short*)vb0 + (size_t)vr * Sk + kc + vg * 8,
                     Vs + seg * 512);
        }
        __syncthreads();

        // S^T chunks: per c (32 k-rows), two f-groups of 16.
        // lane holds sT[mi][fp][r] = P[q = qw+mi*16+l16][k = kc+(2c+fp)*16+quad*4+r]
        short8 pfm[2][2];
#pragma unroll
        for (int c = 0; c < 2; ++c) {
            floatx4 sT[2][2];
#pragma unroll
            for (int fp = 0; fp < 2; ++fp) {
                const int f = c * 2 + fp;
                const int krow = f * 16 + l16;
                short8 kf[4];
#pragma unroll
                for (int cc = 0; cc < 4; ++cc)
                    kf[cc] = *(const short8*)&Ks[krow * 128 + (((cc * 4 + quad) ^ r7) << 3)];
#pragma unroll
                for (int mi = 0; mi < 2; ++mi) {
                    floatx4 s = (floatx4){0.f, 0.f, 0.f, 0.f};
#pragma unroll
                    for (int cc = 0; cc < 4; ++cc)
                        s = __builtin_amdgcn_mfma_f32_16x16x32_bf16(
                            kf[cc], qf[mi][cc], s, 0, 0, 0);
                    sT[mi][fp] = s;
                }
            }

            // pad mask for this 32-k slice (per-lane k = quad*4+r within group)
            const int* pb = pad + (size_t)b * Sk + kc + c * 32 + quad * 4;
            intx4 pv0 = *(const intx4*)pb;
            intx4 pv1 = *(const intx4*)(pb + 16);

#pragma unroll
            for (int mi = 0; mi < 2; ++mi) {
                const int qv = qw + mi * 16 + l16;
#pragma unroll
                for (int fp = 0; fp < 2; ++fp) {
#pragma unroll
                    for (int r = 0; r < 4; ++r) {
                        int kk = kc + (c * 2 + fp) * 16 + quad * 4 + r;
                        bool ok = ((fp ? pv1[r] : pv0[r]) != 0);
                        if (CAUSAL) ok = ok && (kk <= qv);
                        float p = ok ? __builtin_amdgcn_exp2f(sT[mi][fp][r] * sc) : 0.f;
                        sT[mi][fp][r] = p;
                        lsum[mi] += p;
                    }
                }
                // in-register transpose to PV A-frag:
                // wA=(r0,r1|f=2c)  wB=(r2,r3|f=2c)  wC=(r0,r1|f=2c+1)  wD=(r2,r3|f=2c+1)
                unsigned wA = cvtpk_bf16(sT[mi][0][0], sT[mi][0][1]);
                unsigned wB = cvtpk_bf16(sT[mi][0][2], sT[mi][0][3]);
                unsigned wC = cvtpk_bf16(sT[mi][1][0], sT[mi][1][1]);
                unsigned wD = cvtpk_bf16(sT[mi][1][2], sT[mi][1][3]);
                pl32swap(wA, wC);  // wA=[A0,A1,C0,C1] wC=[A2,A3,C2,C3]
                pl16swap(wA, wC);  // wA=[A0,A2,C0,C2]=w0  wC=[A1,A3,C1,C3]=w2
                pl32swap(wB, wD);
                pl16swap(wB, wD);  // wB=w1  wD=w3
                uintx4 t;
                t[0] = wA; t[1] = wB; t[2] = wC; t[3] = wD;
                pfm[mi][c] = __builtin_bit_cast(short8, t);
            }
        }

        // O += P V : V B-frags from swizzled LDS, shared across both m-frags
#pragma unroll
        for (int nf = 0; nf < 8; ++nf) {
            int vrow = nf * 16 + l16;
            short8 vf0 = *(const short8*)&Vs[vrow * 64 + ((quad ^ r7) << 3)];
            short8 vf1 = *(const short8*)&Vs[vrow * 64 + (((4 + quad) ^ r7) << 3)];
#pragma unroll
            for (int mi = 0; mi < 2; ++mi) {
                o[mi][nf] = __builtin_amdgcn_mfma_f32_16x16x32_bf16(
                    pfm[mi][0], vf0, o[mi][nf], 0, 0, 0);
                o[mi][nf] = __builtin_amdgcn_mfma_f32_16x16x32_bf16(
                    pfm[mi][1], vf1, o[mi][nf], 0, 0, 0);
            }
        }
    }

    // write unnormalized O (bf16) + row sums for this split
    bf16* op = Of + (size_t)par * B_ * Sq * DM_;
    float* lp = Ls + (size_t)par * B_ * H_ * Sq;
#pragma unroll
    for (int mi = 0; mi < 2; ++mi) {
        float s = lsum[mi];
        s += __shfl_xor(s, 16);
        s += __shfl_xor(s, 32);
        if (lane < 16)
            lp[(size_t)bh * Sq + qw + mi * 16 + l16] = s;
#pragma unroll
        for (int nf = 0; nf < 8; ++nf)
#pragma unroll
            for (int r = 0; r < 4; ++r) {
                int q = qw + mi * 16 + quad * 4 + r;
                op[(size_t)(b * Sq + q) * DM_ + h * 128 + nf * 16 + l16] =
                    f2b(o[mi][nf][r]);
            }
    }
}

// combine: out = (O0 + O1) / (L0 + L1)
__global__ __launch_bounds__(256) void attn_combine(
    const bf16* __restrict__ Of, const float* __restrict__ Ls,
    bf16* __restrict__ out)
{
    const int row = blockIdx.x;           // b*SD_+q
    const int t = threadIdx.x;
    const int col = t * 4;
    const int h = col >> 7;
    const int b = row >> 11;
    const int q = row & (SD_ - 1);
    const size_t NV = (size_t)B_ * SD_ * DM_;
    const int idx = (b * H_ + h) * SD_ + q;
    float l = Ls[idx] + Ls[B_ * H_ * SD_ + idx];
    float inv = l > 0.f ? 1.f / l : 0.f;
    size_t base = (size_t)row * DM_ + col;
    short4v a0 = *(const short4v*)(Of + base);
    short4v a1 = *(const short4v*)(Of + NV + base);
    short4v r;
#pragma unroll
    for (int i = 0; i < 4; ++i)
        r[i] = f2s((b2f(__builtin_bit_cast(bf16, (short)a0[i])) +
                    b2f(__builtin_bit_cast(bf16, (short)a1[i]))) * inv);
    *(short4v*)(out + base) = r;
}

// ---------------------------------------------------------------------------
// out = LayerNorm(a + b) * g + beta
// ---------------------------------------------------------------------------
template <int A32, int O32>
__global__ __launch_bounds__(256) void add_ln(
    const void* __restrict__ Ap, const bf16* __restrict__ Bv,
    const float* __restrict__ g, const float* __restrict__ be,
    void* __restrict__ outp)
{
    const int D = DM_;
    __shared__ float red[8];
    const size_t row = blockIdx.x;
    const int t = threadIdx.x;

    float x[4];
    {
        float av[4];
        if (A32) {
            floatx4 a4 = *(const floatx4*)((const float*)Ap + row * D + t * 4);
#pragma unroll
            for (int i = 0; i < 4; ++i) av[i] = a4[i];
        } else {
            short4v a4 = *(const short4v*)((const bf16*)Ap + row * D + t * 4);
#pragma unroll
            for (int i = 0; i < 4; ++i)
                av[i] = b2f(__builtin_bit_cast(bf16, (short)a4[i]));
        }
        short4v b4 = *(const short4v*)(Bv + row * D + t * 4);
#pragma unroll
        for (int i = 0; i < 4; ++i)
            x[i] = av[i] + b2f(__builtin_bit_cast(bf16, (short)b4[i]));
    }
    float s = 0.f, s2 = 0.f;
#pragma unroll
    for (int i = 0; i < 4; ++i) { s += x[i]; s2 += x[i] * x[i]; }
#pragma unroll
    for (int off = 32; off >= 1; off >>= 1) {
        s  += __shfl_xor(s, off);
        s2 += __shfl_xor(s2, off);
    }
    const int wave = t >> 6;
    if ((t & 63) == 0) { red[wave] = s; red[4 + wave] = s2; }
    __syncthreads();
    s  = red[0] + red[1] + red[2] + red[3];
    s2 = red[4] + red[5] + red[6] + red[7];
    const float mu   = s * (1.f / D);
    const float var  = s2 * (1.f / D) - mu * mu;
    const float rstd = rsqrtf(var + 1e-5f);
#pragma unroll
    for (int i = 0; i < 4; ++i) {
        int idx = t * 4 + i;
        float v = (x[i] - mu) * rstd * g[idx] + be[idx];
        if (O32) ((float*)outp)[row * D + idx] = v;
        else     ((bf16*)outp)[row * D + idx] = f2b(v);
    }
}

// ---------------------------------------------------------------------------
extern "C" void kernel_launch(void* const* d_in, const int* in_sizes, int n_in,
                              void* d_out, int out_size, void* d_ws, size_t ws_size,
                              hipStream_t stream)
{
    const float* emb    = (const float*)d_in[0];
    const float* enc    = (const float*)d_in[1];
    const int*  in_pad  = (const int*)d_in[2];
    const int*  out_pad = (const int*)d_in[3];
    const float* q1_w = (const float*)d_in[4];  const float* q1_b = (const float*)d_in[5];
    const float* k1_w = (const float*)d_in[6];  const float* k1_b = (const float*)d_in[7];
    const float* v1_w = (const float*)d_in[8];  const float* v1_b = (const float*)d_in[9];
    const float* q2_w = (const float*)d_in[10]; const float* q2_b = (const float*)d_in[11];
    const float* k2_w = (const float*)d_in[12]; const float* k2_b = (const float*)d_in[13];
    const float* v2_w = (const float*)d_in[14]; const float* v2_b = (const float*)d_in[15];
    const float* sa_qw = (const float*)d_in[16]; const float* sa_qb = (const float*)d_in[17];
    const float* sa_kw = (const float*)d_in[18]; const float* sa_kb = (const float*)d_in[19];
    const float* sa_vw = (const float*)d_in[20]; const float* sa_vb = (const float*)d_in[21];
    const float* sa_ow = (const float*)d_in[22]; const float* sa_ob = (const float*)d_in[23];
    const float* ed_qw = (const float*)d_in[24]; const float* ed_qb = (const float*)d_in[25];
    const float* ed_kw = (const float*)d_in[26]; const float* ed_kb = (const float*)d_in[27];
    const float* ed_vw = (const float*)d_in[28]; const float* ed_vb = (const float*)d_in[29];
    const float* ed_ow = (const float*)d_in[30]; const float* ed_ob = (const float*)d_in[31];
    const float* ff_w1 = (const float*)d_in[32]; const float* ff_b1 = (const float*)d_in[33];
    const float* ff_w2 = (const float*)d_in[34]; const float* ff_b2 = (const float*)d_in[35];
    const float* ln1_g = (const float*)d_in[36]; const float* ln1_b = (const float*)d_in[37];
    const float* ln2_g = (const float*)d_in[38]; const float* ln2_b = (const float*)d_in[39];

    const int M = B_ * SD_;                 // 8192
    const size_t MM = (size_t)1024 * 1024;
    bf16* ws = (bf16*)d_ws;

    // ---- workspace layout (bf16 units) ----
    bf16* Wqkv = ws;                 // [3072,1024]
    bf16* Wkv  = ws + 3 * MM;        // [2048,1024]
    bf16* Wq2  = ws + 5 * MM;
    bf16* Wso  = ws + 6 * MM;
    bf16* Weo  = ws + 7 * MM;
    bf16* Wf1  = ws + 8 * MM;
    bf16* Wf2  = ws + 12 * MM;
    float* bQKV = (float*)(ws + 16 * MM);          // 3072 f
    float* bKV  = bQKV + 3072;                     // 2048 f
    float* bQ2  = bKV + 2048;                      // 1024 f
    float* Lsum = bQ2 + 2048;                      // 2*32*2048 f = 512 KB
    bf16* hw   = ws + 17 * MM;
    bf16* ft   = ws + 23 * MM;
    bf16* emb_b = ws + 17 * MM;      // 8M (after composes)
    bf16* enc_b = ws + 25 * MM;      // 8M
    bf16* sqkv  = ws + 33 * MM;      // 24M [8192,3072]
    bf16* skv   = ws + 33 * MM;      // 16M [8192,2048] (after flash1)
    bf16* sq2   = ws + 49 * MM;      // 8M
    bf16* sVt   = ws + 57 * MM;      // 8M  [32][128][2048]
    bf16* attn  = ws + 65 * MM;      // 8M
    bf16* Ofb   = ws + 73 * MM;      // 16M (2 splits x 8M, unnormalized O)
    bf16* s1    = ws + 73 * MM;      // 8M (reused after combine)
    bf16* x     = ws + 89 * MM;      // 8M
    bf16* y     = ws + 33 * MM;      // 8M (after flash2)
    bf16* mid   = ws + 41 * MM;      // 32M
    bf16* f2    = ws + 81 * MM;      // 8M

    auto G = [&](const bf16* Ai, const bf16* Wi, const float* bi, bf16* Ci,
                 int Mi, int Ni, int Ki, bool relu) {
        dim3 grid(Ni / 128, Mi / 128);
        if (relu) gemm_bt<1><<<grid, 256, 0, stream>>>(Ai, Wi, bi, Ci, Mi, Ni, Ki);
        else      gemm_bt<0><<<grid, 256, 0, stream>>>(Ai, Wi, bi, Ci, Mi, Ni, Ki);
    };

    // ---- weight preparation ----
    const float* hsrc[6] = {sa_qw, sa_kw, sa_vw, ed_qw, ed_kw, ed_vw};
    for (int i = 0; i < 6; ++i)
        cvt_f32_bf16<<<dim3(MM / 2048), 256, 0, stream>>>(hsrc[i], hw + i * MM, (int)MM);
    const float* tsrc[6] = {q1_w, k1_w, v1_w, q2_w, k2_w, v2_w};
    for (int i = 0; i < 6; ++i)
        cvt_f32_bf16_T<<<dim3(32, 32), 256, 0, stream>>>(tsrc[i], ft + i * MM);
    bias_comp<<<dim3(1024), 256, 0, stream>>>(sa_qw, q1_b, sa_qb, bQKV);
    bias_comp<<<dim3(1024), 256, 0, stream>>>(sa_kw, k1_b, sa_kb, bQKV + 1024);
    bias_comp<<<dim3(1024), 256, 0, stream>>>(sa_vw, v1_b, sa_vb, bQKV + 2048);
    bias_comp<<<dim3(1024), 256, 0, stream>>>(ed_kw, k2_b, ed_kb, bKV);
    bias_comp<<<dim3(1024), 256, 0, stream>>>(ed_vw, v2_b, ed_vb, bKV + 1024);
    bias_comp<<<dim3(1024), 256, 0, stream>>>(ed_qw, q2_b, ed_qb, bQ2);
    G(hw + 0 * MM, ft + 0 * MM, nullptr, Wqkv + 0 * MM, 1024, 1024, 1024, false);
    G(hw + 1 * MM, ft + 1 * MM, nullptr, Wqkv + 1 * MM, 1024, 1024, 1024, false);
    G(hw + 2 * MM, ft + 2 * MM, nullptr, Wqkv + 2 * MM, 1024, 1024, 1024, false);
    G(hw + 4 * MM, ft + 4 * MM, nullptr, Wkv  + 0 * MM, 1024, 1024, 1024, false);
    G(hw + 5 * MM, ft + 5 * MM, nullptr, Wkv  + 1 * MM, 1024, 1024, 1024, false);
    G(hw + 3 * MM, ft + 3 * MM, nullptr, Wq2,           1024, 1024, 1024, false);
    cvt_f32_bf16<<<dim3(MM / 2048), 256, 0, stream>>>(sa_ow, Wso, (int)MM);
    cvt_f32_bf16<<<dim3(MM / 2048), 256, 0, stream>>>(ed_ow, Weo, (int)MM);
    cvt_f32_bf16<<<dim3(4 * MM / 2048), 256, 0, stream>>>(ff_w1, Wf1, (int)(4 * MM));
    cvt_f32_bf16<<<dim3(4 * MM / 2048), 256, 0, stream>>>(ff_w2, Wf2, (int)(4 * MM));
    cvt_f32_bf16<<<dim3(8 * MM / 2048), 256, 0, stream>>>(emb, emb_b, (int)(8 * MM));
    cvt_f32_bf16<<<dim3(8 * MM / 2048), 256, 0, stream>>>(enc, enc_b, (int)(8 * MM));

    // ---- self attention ----
    G(emb_b, Wqkv, bQKV, sqkv, M, 3072, DM_, false);          // Qh|Kh|Vh
    vtrans<<<dim3(SD_ / 32, 4, B_ * H_), 256, 0, stream>>>(sqkv + 2048, 3072, sVt, SD_);
    flash_attn<1><<<dim3(SD_ / 128, B_ * H_, 2), 256, 0, stream>>>(
        sqkv, 3072, sqkv + 1024, 3072, sVt, out_pad, Ofb, Lsum, SD_, SD_);
    attn_combine<<<dim3(M), 256, 0, stream>>>(Ofb, Lsum, attn);
    G(attn, Wso, sa_ob, s1, M, DM_, DM_, false);
    add_ln<1, 0><<<dim3(M), 256, 0, stream>>>(emb, s1, ln1_g, ln1_b, x);

    // ---- cross attention (residual from emb, per reference) ----
    G(enc_b, Wkv, bKV, skv, M, 2048, DM_, false);             // Kh2|Vh2
    G(x, Wq2, bQ2, sq2, M, DM_, DM_, false);                  // Qh2
    vtrans<<<dim3(SE_ / 32, 4, B_ * H_), 256, 0, stream>>>(skv + 1024, 2048, sVt, SE_);
    flash_attn<0><<<dim3(SD_ / 128, B_ * H_, 2), 256, 0, stream>>>(
        sq2, 1024, skv, 2048, sVt, in_pad, Ofb, Lsum, SD_, SE_);
    attn_combine<<<dim3(M), 256, 0, stream>>>(Ofb, Lsum, attn);
    G(attn, Weo, ed_ob, s1, M, DM_, DM_, false);
    add_ln<1, 0><<<dim3(M), 256, 0, stream>>>(emb, s1, ln2_g, ln2_b, y);

    // ---- FFN (final norm reuses ln2 params, per reference) ----
    G(y, Wf1, ff_b1, mid, M, DFF_, DM_, true);
    G(mid, Wf2, ff_b2, f2, M, DM_, DFF_, false);
    add_ln<0, 1><<<dim3(M), 256, 0, stream>>>(y, f2, ln2_g, ln2_b, d_out);
}

// Round 3
// 1028.391 us; speedup vs baseline: 1.0650x; 1.0650x over previous
//
#include <hip/hip_runtime.h>
#include <hip/hip_bf16.h>

typedef __hip_bfloat16 bf16;
typedef short short8 __attribute__((ext_vector_type(8)));
typedef short short4v __attribute__((ext_vector_type(4)));
typedef float floatx4 __attribute__((ext_vector_type(4)));
typedef int intx4 __attribute__((ext_vector_type(4)));
typedef unsigned int uintx4 __attribute__((ext_vector_type(4)));

#define B_ 4
#define SD_ 2048
#define SE_ 2048
#define DM_ 1024
#define H_ 8
#define DFF_ 4096

__device__ __forceinline__ float b2f(bf16 v) { return __bfloat162float(v); }
__device__ __forceinline__ bf16 f2b(float v) { return __float2bfloat16(v); }
__device__ __forceinline__ short f2s(float v) { return __builtin_bit_cast(short, __float2bfloat16(v)); }

// pack two f32 -> one u32 of 2x bf16 (lo = first arg)
__device__ __forceinline__ unsigned cvtpk_bf16(float lo, float hi) {
    unsigned r;
    asm("v_cvt_pk_bf16_f32 %0, %1, %2" : "=v"(r) : "v"(lo), "v"(hi));
    return r;
}
__device__ __forceinline__ void pl32swap(unsigned &x, unsigned &y) {
    asm("v_permlane32_swap_b32 %0, %1" : "+v"(x), "+v"(y));
}
__device__ __forceinline__ void pl16swap(unsigned &x, unsigned &y) {
    asm("v_permlane16_swap_b32 %0, %1" : "+v"(x), "+v"(y));
}

// async global->LDS, 16B/lane. LDS dest = wave-uniform base + lane*16.
__device__ __forceinline__ void gl_lds16(const short* g, short* l) {
    __builtin_amdgcn_global_load_lds(
        (const __attribute__((address_space(1))) void*)g,
        (__attribute__((address_space(3))) void*)l, 16, 0, 0);
}

// ---------------------------------------------------------------------------
__global__ __launch_bounds__(256) void cvt_f32_bf16(
    const float* __restrict__ in, bf16* __restrict__ out, int n)
{
    int i = (blockIdx.x * 256 + threadIdx.x) * 8;
    if (i >= n) return;
    floatx4 a = *(const floatx4*)(in + i);
    floatx4 b = *(const floatx4*)(in + i + 4);
    short8 r;
#pragma unroll
    for (int k = 0; k < 4; ++k) { r[k] = f2s(a[k]); r[k + 4] = f2s(b[k]); }
    *(short8*)(out + i) = r;
}

// fp32 [1024,1024] -> bf16 transposed
__global__ __launch_bounds__(256) void cvt_f32_bf16_T(
    const float* __restrict__ in, bf16* __restrict__ out)
{
    __shared__ short tl[32][36];
    const int tid = threadIdx.x;
    const int i = tid >> 3;
    const int j = (tid & 7) * 4;
    const int r0 = blockIdx.x * 32, c0 = blockIdx.y * 32;
    floatx4 v = *(const floatx4*)(in + (size_t)(r0 + i) * 1024 + c0 + j);
#pragma unroll
    for (int p = 0; p < 4; ++p) tl[i][j + p] = f2s(v[p]);
    __syncthreads();
    short4v r;
#pragma unroll
    for (int p = 0; p < 4; ++p) r[p] = tl[j + p][i];
    *(short4v*)(out + (size_t)(c0 + i) * 1024 + r0 + j) = r;
}

// composed bias: out[o] = sum_m w[o,m]*bin[m] + badd[o]
__global__ __launch_bounds__(256) void bias_comp(
    const float* __restrict__ w, const float* __restrict__ bin,
    const float* __restrict__ badd, float* __restrict__ out)
{
    __shared__ float red[4];
    const int o = blockIdx.x;
    const int t = threadIdx.x;
    float s = 0.f;
#pragma unroll
    for (int i = t; i < 1024; i += 256) s += w[(size_t)o * 1024 + i] * bin[i];
#pragma unroll
    for (int off = 32; off >= 1; off >>= 1) s += __shfl_xor(s, off);
    if ((t & 63) == 0) red[t >> 6] = s;
    __syncthreads();
    if (t == 0) out[o] = red[0] + red[1] + red[2] + red[3] + badd[o];
}

// ---------------------------------------------------------------------------
// gemm_bt: legacy 128x128 kernel (kept for the small 1024^3 weight-prep GEMMs)
// ---------------------------------------------------------------------------
template <int RELU>
__global__ __launch_bounds__(256) void gemm_bt(
    const bf16* __restrict__ A, const bf16* __restrict__ W,
    const float* __restrict__ bias, bf16* __restrict__ C,
    int M, int N, int K)
{
    __shared__ __align__(16) short As[16 * 512];
    __shared__ __align__(16) short Ws[16 * 512];

    const int tid  = threadIdx.x;
    const int lane = tid & 63;
    const int wave = tid >> 6;
    const int quad = lane >> 4;
    const int l16  = lane & 15;
    const int r7   = l16 & 7;
    const int bm0  = blockIdx.y * 128;
    const int bn0  = blockIdx.x * 128;
    const int wm   = (wave >> 1) * 64;
    const int wn   = (wave & 1) * 64;

    const int scol = (((lane & 7) ^ (lane >> 3)) * 8);
    const short* Ag = (const short*)A + (size_t)(bm0 + wave * 32 + (lane >> 3)) * K + scol;
    const short* Wg = (const short*)W + (size_t)(bn0 + wave * 32 + (lane >> 3)) * K + scol;
    short* Al = As + (wave * 4) * 512;
    short* Wl = Ws + (wave * 4) * 512;

    floatx4 acc[4][4];
#pragma unroll
    for (int i = 0; i < 4; ++i)
#pragma unroll
        for (int j = 0; j < 4; ++j)
            acc[i][j] = (floatx4){0.f, 0.f, 0.f, 0.f};

    for (int k0 = 0; k0 < K; k0 += 64) {
        __syncthreads();
#pragma unroll
        for (int s = 0; s < 4; ++s) {
            gl_lds16(Ag + k0 + (size_t)s * 8 * K, Al + s * 512);
            gl_lds16(Wg + k0 + (size_t)s * 8 * K, Wl + s * 512);
        }
        __syncthreads();
#pragma unroll
        for (int kk = 0; kk < 64; kk += 32) {
            short8 af[4], bg[4];
#pragma unroll
            for (int i = 0; i < 4; ++i) {
                int row = wm + i * 16 + l16;
                af[i] = *(const short8*)&As[(row >> 3) * 512 + r7 * 64 +
                                            (((quad + (kk >> 3)) ^ r7) << 3)];
            }
#pragma unroll
            for (int j = 0; j < 4; ++j) {
                int row = wn + j * 16 + l16;
                bg[j] = *(const short8*)&Ws[(row >> 3) * 512 + r7 * 64 +
                                            (((quad + (kk >> 3)) ^ r7) << 3)];
            }
#pragma unroll
            for (int i = 0; i < 4; ++i)
#pragma unroll
                for (int j = 0; j < 4; ++j)
                    acc[i][j] = __builtin_amdgcn_mfma_f32_16x16x32_bf16(
                        af[i], bg[j], acc[i][j], 0, 0, 0);
        }
    }

#pragma unroll
    for (int j = 0; j < 4; ++j) {
        int col = bn0 + wn + j * 16 + l16;
        float bv = bias ? bias[col] : 0.f;
#pragma unroll
        for (int i = 0; i < 4; ++i) {
            int row0 = bm0 + wm + i * 16 + quad * 4;
#pragma unroll
            for (int r = 0; r < 4; ++r) {
                float v = acc[i][j][r] + bv;
                if (RELU) v = fmaxf(v, 0.f);
                C[(size_t)(row0 + r) * N + col] = f2b(v);
            }
        }
    }
}

// ---------------------------------------------------------------------------
// gemm256: C = act(A @ W^T + bias), BM=256 x BN=128 x BK=64, 8 waves.
// Triple-buffered LDS (144 KB): staging runs 2 K-tiles ahead -> counted
// vmcnt(6), never drained in the main loop (T3+T4).  Per tile, 2 phases of
// {ds_read subtile | 3x global_load_lds(t+2) | barrier | lgkmcnt(0) |
//  setprio(1) 16 MFMA setprio(0) | barrier}.  XOR-swizzled LDS blocks
// (conflict-free b128 frags), XCD-chunked block swizzle (T1).
// Invariant: at each tile end, outstanding vmem = 6(t+1)+6(t+2)=12;
// vmcnt(6) retires exactly tile t+1's loads.  Buffer (t+2)%3 overwrites
// tile t-1, whose reads completed before tile t-1's end barrier.
// ---------------------------------------------------------------------------
template <int RELU>
__global__ __launch_bounds__(512, 2) void gemm256(
    const bf16* __restrict__ A, const bf16* __restrict__ W,
    const float* __restrict__ bias, bf16* __restrict__ C,
    int M, int N, int K)
{
    __shared__ __align__(16) short L[3 * 24576];   // 3 x (A 256x64 + B 128x64)

    const int tid  = threadIdx.x;
    const int lane = tid & 63;
    const int wave = tid >> 6;       // 0..7
    const int quad = lane >> 4;
    const int l16  = lane & 15;
    const int r7   = l16 & 7;
    const int wm   = wave >> 1;      // 0..3  (m-quarter)
    const int wn   = wave & 1;       // 0..1  (n-half)

    // XCD-chunked block swizzle (grids here are always %8 == 0)
    const int gx  = gridDim.x;
    const int nwg = gx * gridDim.y;
    int wg = blockIdx.y * gx + blockIdx.x;
    if ((nwg & 7) == 0) wg = (wg & 7) * (nwg >> 3) + (wg >> 3);
    const int bn0 = (wg % gx) * 128;
    const int bm0 = (wg / gx) * 256;

    // staging bases: lane -> row (lane>>3), swizzled block pos (lane&7)
    const int scol = (((lane & 7) ^ ((lane >> 3) & 7)) * 8);
    const short* Ag = (const short*)A + (size_t)(bm0 + wave * 32 + (lane >> 3)) * K + scol;
    const short* Wg = (const short*)W + (size_t)(bn0 + wave * 16 + (lane >> 3)) * K + scol;
    const int aw = (wave * 32) * 64;           // this wave's A rows in LDS
    const int bw = 16384 + (wave * 16) * 64;   // this wave's B rows in LDS

    floatx4 acc[4][4];
#pragma unroll
    for (int i = 0; i < 4; ++i)
#pragma unroll
        for (int j = 0; j < 4; ++j)
            acc[i][j] = (floatx4){0.f, 0.f, 0.f, 0.f};

    const int T = K / 64;

    // ---- prologue: stage tile0 -> buf0, tile1 -> buf1 (12 loads/wave) ----
#pragma unroll
    for (int i = 0; i < 4; ++i) gl_lds16(Ag + (size_t)(i * 8) * K, L + aw + i * 8 * 64);
#pragma unroll
    for (int i = 0; i < 2; ++i) gl_lds16(Wg + (size_t)(i * 8) * K, L + bw + i * 8 * 64);
#pragma unroll
    for (int i = 0; i < 4; ++i) gl_lds16(Ag + 64 + (size_t)(i * 8) * K, L + 24576 + aw + i * 8 * 64);
#pragma unroll
    for (int i = 0; i < 2; ++i) gl_lds16(Wg + 64 + (size_t)(i * 8) * K, L + 24576 + bw + i * 8 * 64);
    asm volatile("s_waitcnt vmcnt(6)" ::: "memory");   // tile0 landed, tile1 in flight
    __builtin_amdgcn_s_barrier();

    int cur = 0, stg = 2;
    for (int t = 0; t < T; ++t) {
        __builtin_amdgcn_sched_barrier(0);
        const int kt = (t + 2 < T) ? (t + 2) : (T - 1);   // clamped prefetch tile
        const size_t kg = (size_t)kt * 64;
        const short* Ac = L + cur * 24576;
        const short* Bc = Ac + 16384;
        short* As_s = L + stg * 24576 + aw;
        short* Bs_s = L + stg * 24576 + bw;

        short8 af[2][2], bf[4][2];

        // ---------------- phase 0: m-frags 0,1 ----------------
#pragma unroll
        for (int mi = 0; mi < 2; ++mi)
#pragma unroll
            for (int ks = 0; ks < 2; ++ks)
                af[mi][ks] = *(const short8*)&Ac[(wm * 64 + mi * 16 + l16) * 64 +
                                                (((ks * 4 + quad) ^ r7) << 3)];
#pragma unroll
        for (int nf = 0; nf < 4; ++nf)
#pragma unroll
            for (int ks = 0; ks < 2; ++ks)
                bf[nf][ks] = *(const short8*)&Bc[(wn * 64 + nf * 16 + l16) * 64 +
                                                (((ks * 4 + quad) ^ r7) << 3)];
        gl_lds16(Ag + kg, As_s);
        gl_lds16(Ag + kg + (size_t)8 * K, As_s + 8 * 64);
        gl_lds16(Wg + kg, Bs_s);
        __builtin_amdgcn_s_barrier();
        asm volatile("s_waitcnt lgkmcnt(0)" ::: "memory");
        __builtin_amdgcn_sched_barrier(0);
        __builtin_amdgcn_s_setprio(1);
#pragma unroll
        for (int ks = 0; ks < 2; ++ks)
#pragma unroll
            for (int mi = 0; mi < 2; ++mi)
#pragma unroll
                for (int nf = 0; nf < 4; ++nf)
                    acc[mi][nf] = __builtin_amdgcn_mfma_f32_16x16x32_bf16(
                        af[mi][ks], bf[nf][ks], acc[mi][nf], 0, 0, 0);
        __builtin_amdgcn_s_setprio(0);
        __builtin_amdgcn_s_barrier();

        // ---------------- phase 1: m-frags 2,3 ----------------
#pragma unroll
        for (int mi = 0; mi < 2; ++mi)
#pragma unroll
            for (int ks = 0; ks < 2; ++ks)
                af[mi][ks] = *(const short8*)&Ac[(wm * 64 + (2 + mi) * 16 + l16) * 64 +
                                                (((ks * 4 + quad) ^ r7) << 3)];
        gl_lds16(Ag + kg + (size_t)16 * K, As_s + 16 * 64);
        gl_lds16(Ag + kg + (size_t)24 * K, As_s + 24 * 64);
        gl_lds16(Wg + kg + (size_t)8 * K, Bs_s + 8 * 64);
        __builtin_amdgcn_s_barrier();
        asm volatile("s_waitcnt lgkmcnt(0)" ::: "memory");
        __builtin_amdgcn_sched_barrier(0);
        __builtin_amdgcn_s_setprio(1);
#pragma unroll
        for (int ks = 0; ks < 2; ++ks)
#pragma unroll
            for (int mi = 0; mi < 2; ++mi)
#pragma unroll
                for (int nf = 0; nf < 4; ++nf)
                    acc[2 + mi][nf] = __builtin_amdgcn_mfma_f32_16x16x32_bf16(
                        af[mi][ks], bf[nf][ks], acc[2 + mi][nf], 0, 0, 0);
        __builtin_amdgcn_s_setprio(0);
        asm volatile("s_waitcnt vmcnt(6)" ::: "memory");  // tile t+1 landed
        __builtin_amdgcn_s_barrier();

        cur = (cur == 2) ? 0 : cur + 1;
        stg = (stg == 2) ? 0 : stg + 1;
    }

    // ---- epilogue ----
#pragma unroll
    for (int nf = 0; nf < 4; ++nf) {
        int col = bn0 + wn * 64 + nf * 16 + l16;
        float bv = bias ? bias[col] : 0.f;
#pragma unroll
        for (int mf = 0; mf < 4; ++mf) {
            int row0 = bm0 + wm * 64 + mf * 16 + quad * 4;
#pragma unroll
            for (int r = 0; r < 4; ++r) {
                float v = acc[mf][nf][r] + bv;
                if (RELU) v = fmaxf(v, 0.f);
                C[(size_t)(row0 + r) * N + col] = f2b(v);
            }
        }
    }
}

// ---------------------------------------------------------------------------
// V transpose: in rows [B*S, str] (head h at col h*128) -> out [B*H][128][S]
// ---------------------------------------------------------------------------
__global__ __launch_bounds__(256) void vtrans(
    const bf16* __restrict__ in, int str, bf16* __restrict__ out, int S)
{
    __shared__ short t[32][36];
    const int tid = threadIdx.x;
    const int s0  = blockIdx.x * 32;
    const int d0  = blockIdx.y * 32;
    const int bh  = blockIdx.z;
    const int b = bh >> 3, h = bh & 7;
    const int i = tid >> 3;
    const int j = (tid & 7) * 4;

    *(short4v*)&t[i][j] =
        *(const short4v*)(in + (size_t)(b * S + s0 + i) * str + h * 128 + d0 + j);
    __syncthreads();
    short4v r;
#pragma unroll
    for (int p = 0; p < 4; ++p) r[p] = t[j + p][i];
    *(short4v*)(out + ((size_t)bh * 128 + d0 + i) * S + s0 + j) = r;
}

// ---------------------------------------------------------------------------
// Flash attention v7: operand-swapped QK^T (S^T = K Q^T); in-register P
// transpose via v_cvt_pk_bf16_f32 + permlane32/16_swap.  Unnormalized O +
// row-sums, K-split x2, gl_lds staging with XOR bank swizzle.
// ---------------------------------------------------------------------------
template <int CAUSAL>
__global__ __launch_bounds__(256) void flash_attn(
    const bf16* __restrict__ Q, int qstr, const bf16* __restrict__ K, int kstr,
    const bf16* __restrict__ Vt, const int* __restrict__ pad,
    bf16* __restrict__ Of, float* __restrict__ Ls, int Sq, int Sk)
{
    __shared__ __align__(16) short Ks[64 * 128];   // 16 KB, swizzled
    __shared__ __align__(16) short Vs[128 * 64];   // 16 KB, swizzled

    const int tid  = threadIdx.x;
    const int lane = tid & 63;
    const int wave = tid >> 6;
    const int quad = lane >> 4;
    const int l16  = lane & 15;
    const int r7   = l16 & 7;
    const int bh   = blockIdx.y;
    const int b    = bh >> 3;
    const int h    = bh & 7;
    const int par  = blockIdx.z;
    int tile = blockIdx.x;
    if (CAUSAL) tile = (tile & 1) ? (gridDim.x - 1 - (tile >> 1)) : (tile >> 1);
    const int q0 = tile * 128;
    const int qw = q0 + wave * 32;

    short8 qf[2][4];
#pragma unroll
    for (int mi = 0; mi < 2; ++mi) {
        const bf16* qb = Q + (size_t)(b * Sq + qw + mi * 16 + l16) * qstr + h * 128;
#pragma unroll
        for (int c = 0; c < 4; ++c)
            qf[mi][c] = *(const short8*)(qb + c * 32 + quad * 8);
    }

    floatx4 o[2][8];
#pragma unroll
    for (int mi = 0; mi < 2; ++mi)
#pragma unroll
        for (int nf = 0; nf < 8; ++nf) o[mi][nf] = (floatx4){0.f, 0.f, 0.f, 0.f};
    float lsum[2] = {0.f, 0.f};

    const float sc = 0.08838834764831845f * 1.4426950408889634f;  // log2 scale
    int kEnd = Sk;
    if (CAUSAL && q0 + 128 < Sk) kEnd = q0 + 128;

    const bf16* vb0 = Vt + (size_t)bh * 128 * Sk;

    for (int ci = par; ci * 64 < kEnd; ci += 2) {
        const int kc = ci * 64;
        __syncthreads();
#pragma unroll
        for (int s = 0; s < 4; ++s) {
            int seg = wave * 4 + s;
            int kr = seg * 4 + (lane >> 4);
            int kg = (lane & 15) ^ (kr & 7);
            gl_lds16((const short*)K + (size_t)(b * Sk + kc + kr) * kstr + h * 128 + kg * 8,
                     Ks + seg * 512);
            int vr = seg * 8 + (lane >> 3);
            int vg = (lane & 7) ^ (vr & 7);
            gl_lds16((const short*)vb0 + (size_t)vr * Sk + kc + vg * 8,
                     Vs + seg * 512);
        }
        __syncthreads();

        short8 pfm[2][2];
#pragma unroll
        for (int c = 0; c < 2; ++c) {
            floatx4 sT[2][2];
#pragma unroll
            for (int fp = 0; fp < 2; ++fp) {
                const int f = c * 2 + fp;
                const int krow = f * 16 + l16;
                short8 kf[4];
#pragma unroll
                for (int cc = 0; cc < 4; ++cc)
                    kf[cc] = *(const short8*)&Ks[krow * 128 + (((cc * 4 + quad) ^ r7) << 3)];
#pragma unroll
                for (int mi = 0; mi < 2; ++mi) {
                    floatx4 s = (floatx4){0.f, 0.f, 0.f, 0.f};
#pragma unroll
                    for (int cc = 0; cc < 4; ++cc)
                        s = __builtin_amdgcn_mfma_f32_16x16x32_bf16(
                            kf[cc], qf[mi][cc], s, 0, 0, 0);
                    sT[mi][fp] = s;
                }
            }

            const int* pb = pad + (size_t)b * Sk + kc + c * 32 + quad * 4;
            intx4 pv0 = *(const intx4*)pb;
            intx4 pv1 = *(const intx4*)(pb + 16);

#pragma unroll
            for (int mi = 0; mi < 2; ++mi) {
                const int qv = qw + mi * 16 + l16;
#pragma unroll
                for (int fp = 0; fp < 2; ++fp) {
#pragma unroll
                    for (int r = 0; r < 4; ++r) {
                        int kk = kc + (c * 2 + fp) * 16 + quad * 4 + r;
                        bool ok = ((fp ? pv1[r] : pv0[r]) != 0);
                        if (CAUSAL) ok = ok && (kk <= qv);
                        float p = ok ? __builtin_amdgcn_exp2f(sT[mi][fp][r] * sc) : 0.f;
                        sT[mi][fp][r] = p;
                        lsum[mi] += p;
                    }
                }
                unsigned wA = cvtpk_bf16(sT[mi][0][0], sT[mi][0][1]);
                unsigned wB = cvtpk_bf16(sT[mi][0][2], sT[mi][0][3]);
                unsigned wC = cvtpk_bf16(sT[mi][1][0], sT[mi][1][1]);
                unsigned wD = cvtpk_bf16(sT[mi][1][2], sT[mi][1][3]);
                pl32swap(wA, wC);
                pl16swap(wA, wC);
                pl32swap(wB, wD);
                pl16swap(wB, wD);
                uintx4 t;
                t[0] = wA; t[1] = wB; t[2] = wC; t[3] = wD;
                pfm[mi][c] = __builtin_bit_cast(short8, t);
            }
        }

#pragma unroll
        for (int nf = 0; nf < 8; ++nf) {
            int vrow = nf * 16 + l16;
            short8 vf0 = *(const short8*)&Vs[vrow * 64 + ((quad ^ r7) << 3)];
            short8 vf1 = *(const short8*)&Vs[vrow * 64 + (((4 + quad) ^ r7) << 3)];
#pragma unroll
            for (int mi = 0; mi < 2; ++mi) {
                o[mi][nf] = __builtin_amdgcn_mfma_f32_16x16x32_bf16(
                    pfm[mi][0], vf0, o[mi][nf], 0, 0, 0);
                o[mi][nf] = __builtin_amdgcn_mfma_f32_16x16x32_bf16(
                    pfm[mi][1], vf1, o[mi][nf], 0, 0, 0);
            }
        }
    }

    bf16* op = Of + (size_t)par * B_ * Sq * DM_;
    float* lp = Ls + (size_t)par * B_ * H_ * Sq;
#pragma unroll
    for (int mi = 0; mi < 2; ++mi) {
        float s = lsum[mi];
        s += __shfl_xor(s, 16);
        s += __shfl_xor(s, 32);
        if (lane < 16)
            lp[(size_t)bh * Sq + qw + mi * 16 + l16] = s;
#pragma unroll
        for (int nf = 0; nf < 8; ++nf)
#pragma unroll
            for (int r = 0; r < 4; ++r) {
                int q = qw + mi * 16 + quad * 4 + r;
                op[(size_t)(b * Sq + q) * DM_ + h * 128 + nf * 16 + l16] =
                    f2b(o[mi][nf][r]);
            }
    }
}

// combine: out = (O0 + O1) / (L0 + L1)
__global__ __launch_bounds__(256) void attn_combine(
    const bf16* __restrict__ Of, const float* __restrict__ Ls,
    bf16* __restrict__ out)
{
    const int row = blockIdx.x;           // b*SD_+q
    const int t = threadIdx.x;
    const int col = t * 4;
    const int h = col >> 7;
    const int b = row >> 11;
    const int q = row & (SD_ - 1);
    const size_t NV = (size_t)B_ * SD_ * DM_;
    const int idx = (b * H_ + h) * SD_ + q;
    float l = Ls[idx] + Ls[B_ * H_ * SD_ + idx];
    float inv = l > 0.f ? 1.f / l : 0.f;
    size_t base = (size_t)row * DM_ + col;
    short4v a0 = *(const short4v*)(Of + base);
    short4v a1 = *(const short4v*)(Of + NV + base);
    short4v r;
#pragma unroll
    for (int i = 0; i < 4; ++i)
        r[i] = f2s((b2f(__builtin_bit_cast(bf16, (short)a0[i])) +
                    b2f(__builtin_bit_cast(bf16, (short)a1[i]))) * inv);
    *(short4v*)(out + base) = r;
}

// ---------------------------------------------------------------------------
// out = LayerNorm(a + b) * g + beta
// ---------------------------------------------------------------------------
template <int A32, int O32>
__global__ __launch_bounds__(256) void add_ln(
    const void* __restrict__ Ap, const bf16* __restrict__ Bv,
    const float* __restrict__ g, const float* __restrict__ be,
    void* __restrict__ outp)
{
    const int D = DM_;
    __shared__ float red[8];
    const size_t row = blockIdx.x;
    const int t = threadIdx.x;

    float x[4];
    {
        float av[4];
        if (A32) {
            floatx4 a4 = *(const floatx4*)((const float*)Ap + row * D + t * 4);
#pragma unroll
            for (int i = 0; i < 4; ++i) av[i] = a4[i];
        } else {
            short4v a4 = *(const short4v*)((const bf16*)Ap + row * D + t * 4);
#pragma unroll
            for (int i = 0; i < 4; ++i)
                av[i] = b2f(__builtin_bit_cast(bf16, (short)a4[i]));
        }
        short4v b4 = *(const short4v*)(Bv + row * D + t * 4);
#pragma unroll
        for (int i = 0; i < 4; ++i)
            x[i] = av[i] + b2f(__builtin_bit_cast(bf16, (short)b4[i]));
    }
    float s = 0.f, s2 = 0.f;
#pragma unroll
    for (int i = 0; i < 4; ++i) { s += x[i]; s2 += x[i] * x[i]; }
#pragma unroll
    for (int off = 32; off >= 1; off >>= 1) {
        s  += __shfl_xor(s, off);
        s2 += __shfl_xor(s2, off);
    }
    const int wave = t >> 6;
    if ((t & 63) == 0) { red[wave] = s; red[4 + wave] = s2; }
    __syncthreads();
    s  = red[0] + red[1] + red[2] + red[3];
    s2 = red[4] + red[5] + red[6] + red[7];
    const float mu   = s * (1.f / D);
    const float var  = s2 * (1.f / D) - mu * mu;
    const float rstd = rsqrtf(var + 1e-5f);
#pragma unroll
    for (int i = 0; i < 4; ++i) {
        int idx = t * 4 + i;
        float v = (x[i] - mu) * rstd * g[idx] + be[idx];
        if (O32) ((float*)outp)[row * D + idx] = v;
        else     ((bf16*)outp)[row * D + idx] = f2b(v);
    }
}

// ---------------------------------------------------------------------------
extern "C" void kernel_launch(void* const* d_in, const int* in_sizes, int n_in,
                              void* d_out, int out_size, void* d_ws, size_t ws_size,
                              hipStream_t stream)
{
    const float* emb    = (const float*)d_in[0];
    const float* enc    = (const float*)d_in[1];
    const int*  in_pad  = (const int*)d_in[2];
    const int*  out_pad = (const int*)d_in[3];
    const float* q1_w = (const float*)d_in[4];  const float* q1_b = (const float*)d_in[5];
    const float* k1_w = (const float*)d_in[6];  const float* k1_b = (const float*)d_in[7];
    const float* v1_w = (const float*)d_in[8];  const float* v1_b = (const float*)d_in[9];
    const float* q2_w = (const float*)d_in[10]; const float* q2_b = (const float*)d_in[11];
    const float* k2_w = (const float*)d_in[12]; const float* k2_b = (const float*)d_in[13];
    const float* v2_w = (const float*)d_in[14]; const float* v2_b = (const float*)d_in[15];
    const float* sa_qw = (const float*)d_in[16]; const float* sa_qb = (const float*)d_in[17];
    const float* sa_kw = (const float*)d_in[18]; const float* sa_kb = (const float*)d_in[19];
    const float* sa_vw = (const float*)d_in[20]; const float* sa_vb = (const float*)d_in[21];
    const float* sa_ow = (const float*)d_in[22]; const float* sa_ob = (const float*)d_in[23];
    const float* ed_qw = (const float*)d_in[24]; const float* ed_qb = (const float*)d_in[25];
    const float* ed_kw = (const float*)d_in[26]; const float* ed_kb = (const float*)d_in[27];
    const float* ed_vw = (const float*)d_in[28]; const float* ed_vb = (const float*)d_in[29];
    const float* ed_ow = (const float*)d_in[30]; const float* ed_ob = (const float*)d_in[31];
    const float* ff_w1 = (const float*)d_in[32]; const float* ff_b1 = (const float*)d_in[33];
    const float* ff_w2 = (const float*)d_in[34]; const float* ff_b2 = (const float*)d_in[35];
    const float* ln1_g = (const float*)d_in[36]; const float* ln1_b = (const float*)d_in[37];
    const float* ln2_g = (const float*)d_in[38]; const float* ln2_b = (const float*)d_in[39];

    const int M = B_ * SD_;                 // 8192
    const size_t MM = (size_t)1024 * 1024;
    bf16* ws = (bf16*)d_ws;

    // ---- workspace layout (bf16 units) ----
    bf16* Wqkv = ws;                 // [3072,1024]
    bf16* Wkv  = ws + 3 * MM;        // [2048,1024]
    bf16* Wq2  = ws + 5 * MM;
    bf16* Wso  = ws + 6 * MM;
    bf16* Weo  = ws + 7 * MM;
    bf16* Wf1  = ws + 8 * MM;
    bf16* Wf2  = ws + 12 * MM;
    float* bQKV = (float*)(ws + 16 * MM);          // 3072 f
    float* bKV  = bQKV + 3072;                     // 2048 f
    float* bQ2  = bKV + 2048;                      // 1024 f
    float* Lsum = bQ2 + 2048;                      // 2*32*2048 f = 512 KB
    bf16* hw   = ws + 17 * MM;
    bf16* ft   = ws + 23 * MM;
    bf16* emb_b = ws + 17 * MM;      // 8M (after composes)
    bf16* enc_b = ws + 25 * MM;      // 8M
    bf16* sqkv  = ws + 33 * MM;      // 24M [8192,3072]
    bf16* skv   = ws + 33 * MM;      // 16M [8192,2048] (after flash1)
    bf16* sq2   = ws + 49 * MM;      // 8M
    bf16* sVt   = ws + 57 * MM;      // 8M  [32][128][2048]
    bf16* attn  = ws + 65 * MM;      // 8M
    bf16* Ofb   = ws + 73 * MM;      // 16M (2 splits x 8M, unnormalized O)
    bf16* s1    = ws + 73 * MM;      // 8M (reused after combine)
    bf16* x     = ws + 89 * MM;      // 8M
    bf16* y     = ws + 33 * MM;      // 8M (after flash2)
    bf16* mid   = ws + 41 * MM;      // 32M
    bf16* f2    = ws + 81 * MM;      // 8M

    // main GEMMs: 256x128-tile pipelined kernel
    auto G = [&](const bf16* Ai, const bf16* Wi, const float* bi, bf16* Ci,
                 int Mi, int Ni, int Ki, bool relu) {
        dim3 grid(Ni / 128, Mi / 256);
        if (relu) gemm256<1><<<grid, 512, 0, stream>>>(Ai, Wi, bi, Ci, Mi, Ni, Ki);
        else      gemm256<0><<<grid, 512, 0, stream>>>(Ai, Wi, bi, Ci, Mi, Ni, Ki);
    };
    // weight-prep GEMMs (1024^3): legacy 128x128 kernel (better grid fill)
    auto Gp = [&](const bf16* Ai, const bf16* Wi, bf16* Ci) {
        dim3 grid(8, 8);
        gemm_bt<0><<<grid, 256, 0, stream>>>(Ai, Wi, nullptr, Ci, 1024, 1024, 1024);
    };

    // ---- weight preparation ----
    const float* hsrc[6] = {sa_qw, sa_kw, sa_vw, ed_qw, ed_kw, ed_vw};
    for (int i = 0; i < 6; ++i)
        cvt_f32_bf16<<<dim3(MM / 2048), 256, 0, stream>>>(hsrc[i], hw + i * MM, (int)MM);
    const float* tsrc[6] = {q1_w, k1_w, v1_w, q2_w, k2_w, v2_w};
    for (int i = 0; i < 6; ++i)
        cvt_f32_bf16_T<<<dim3(32, 32), 256, 0, stream>>>(tsrc[i], ft + i * MM);
    bias_comp<<<dim3(1024), 256, 0, stream>>>(sa_qw, q1_b, sa_qb, bQKV);
    bias_comp<<<dim3(1024), 256, 0, stream>>>(sa_kw, k1_b, sa_kb, bQKV + 1024);
    bias_comp<<<dim3(1024), 256, 0, stream>>>(sa_vw, v1_b, sa_vb, bQKV + 2048);
    bias_comp<<<dim3(1024), 256, 0, stream>>>(ed_kw, k2_b, ed_kb, bKV);
    bias_comp<<<dim3(1024), 256, 0, stream>>>(ed_vw, v2_b, ed_vb, bKV + 1024);
    bias_comp<<<dim3(1024), 256, 0, stream>>>(ed_qw, q2_b, ed_qb, bQ2);
    Gp(hw + 0 * MM, ft + 0 * MM, Wqkv + 0 * MM);
    Gp(hw + 1 * MM, ft + 1 * MM, Wqkv + 1 * MM);
    Gp(hw + 2 * MM, ft + 2 * MM, Wqkv + 2 * MM);
    Gp(hw + 4 * MM, ft + 4 * MM, Wkv  + 0 * MM);
    Gp(hw + 5 * MM, ft + 5 * MM, Wkv  + 1 * MM);
    Gp(hw + 3 * MM, ft + 3 * MM, Wq2);
    cvt_f32_bf16<<<dim3(MM / 2048), 256, 0, stream>>>(sa_ow, Wso, (int)MM);
    cvt_f32_bf16<<<dim3(MM / 2048), 256, 0, stream>>>(ed_ow, Weo, (int)MM);
    cvt_f32_bf16<<<dim3(4 * MM / 2048), 256, 0, stream>>>(ff_w1, Wf1, (int)(4 * MM));
    cvt_f32_bf16<<<dim3(4 * MM / 2048), 256, 0, stream>>>(ff_w2, Wf2, (int)(4 * MM));
    cvt_f32_bf16<<<dim3(8 * MM / 2048), 256, 0, stream>>>(emb, emb_b, (int)(8 * MM));
    cvt_f32_bf16<<<dim3(8 * MM / 2048), 256, 0, stream>>>(enc, enc_b, (int)(8 * MM));

    // ---- self attention ----
    G(emb_b, Wqkv, bQKV, sqkv, M, 3072, DM_, false);          // Qh|Kh|Vh
    vtrans<<<dim3(SD_ / 32, 4, B_ * H_), 256, 0, stream>>>(sqkv + 2048, 3072, sVt, SD_);
    flash_attn<1><<<dim3(SD_ / 128, B_ * H_, 2), 256, 0, stream>>>(
        sqkv, 3072, sqkv + 1024, 3072, sVt, out_pad, Ofb, Lsum, SD_, SD_);
    attn_combine<<<dim3(M), 256, 0, stream>>>(Ofb, Lsum, attn);
    G(attn, Wso, sa_ob, s1, M, DM_, DM_, false);
    add_ln<1, 0><<<dim3(M), 256, 0, stream>>>(emb, s1, ln1_g, ln1_b, x);

    // ---- cross attention (residual from emb, per reference) ----
    G(enc_b, Wkv, bKV, skv, M, 2048, DM_, false);             // Kh2|Vh2
    G(x, Wq2, bQ2, sq2, M, DM_, DM_, false);                  // Qh2
    vtrans<<<dim3(SE_ / 32, 4, B_ * H_), 256, 0, stream>>>(skv + 1024, 2048, sVt, SE_);
    flash_attn<0><<<dim3(SD_ / 128, B_ * H_, 2), 256, 0, stream>>>(
        sq2, 1024, skv, 2048, sVt, in_pad, Ofb, Lsum, SD_, SE_);
    attn_combine<<<dim3(M), 256, 0, stream>>>(Ofb, Lsum, attn);
    G(attn, Weo, ed_ob, s1, M, DM_, DM_, false);
    add_ln<1, 0><<<dim3(M), 256, 0, stream>>>(emb, s1, ln2_g, ln2_b, y);

    // ---- FFN (final norm reuses ln2 params, per reference) ----
    G(y, Wf1, ff_b1, mid, M, DFF_, DM_, true);
    G(mid, Wf2, ff_b2, f2, M, DM_, DFF_, false);
    add_ln<0, 1><<<dim3(M), 256, 0, stream>>>(y, f2, ln2_g, ln2_b, d_out);
}

// Round 4
// 1000.829 us; speedup vs baseline: 1.0944x; 1.0275x over previous
//
#include <hip/hip_runtime.h>
#include <hip/hip_bf16.h>

typedef __hip_bfloat16 bf16;
typedef short short8 __attribute__((ext_vector_type(8)));
typedef short short4v __attribute__((ext_vector_type(4)));
typedef float floatx4 __attribute__((ext_vector_type(4)));
typedef int intx4 __attribute__((ext_vector_type(4)));
typedef unsigned int uintx4 __attribute__((ext_vector_type(4)));

#define B_ 4
#define SD_ 2048
#define SE_ 2048
#define DM_ 1024
#define H_ 8
#define DFF_ 4096

__device__ __forceinline__ float b2f(bf16 v) { return __bfloat162float(v); }
__device__ __forceinline__ bf16 f2b(float v) { return __float2bfloat16(v); }
__device__ __forceinline__ short f2s(float v) { return __builtin_bit_cast(short, __float2bfloat16(v)); }

// pack two f32 -> one u32 of 2x bf16 (lo = first arg)
__device__ __forceinline__ unsigned cvtpk_bf16(float lo, float hi) {
    unsigned r;
    asm("v_cvt_pk_bf16_f32 %0, %1, %2" : "=v"(r) : "v"(lo), "v"(hi));
    return r;
}
__device__ __forceinline__ void pl32swap(unsigned &x, unsigned &y) {
    asm("v_permlane32_swap_b32 %0, %1" : "+v"(x), "+v"(y));
}
__device__ __forceinline__ void pl16swap(unsigned &x, unsigned &y) {
    asm("v_permlane16_swap_b32 %0, %1" : "+v"(x), "+v"(y));
}

// async global->LDS, 16B/lane. LDS dest = wave-uniform base + lane*16.
__device__ __forceinline__ void gl_lds16(const short* g, short* l) {
    __builtin_amdgcn_global_load_lds(
        (const __attribute__((address_space(1))) void*)g,
        (__attribute__((address_space(3))) void*)l, 16, 0, 0);
}

// ---------------------------------------------------------------------------
__global__ __launch_bounds__(256) void cvt_f32_bf16(
    const float* __restrict__ in, bf16* __restrict__ out, int n)
{
    int i = (blockIdx.x * 256 + threadIdx.x) * 8;
    if (i >= n) return;
    floatx4 a = *(const floatx4*)(in + i);
    floatx4 b = *(const floatx4*)(in + i + 4);
    short8 r;
#pragma unroll
    for (int k = 0; k < 4; ++k) { r[k] = f2s(a[k]); r[k + 4] = f2s(b[k]); }
    *(short8*)(out + i) = r;
}

// fp32 [1024,1024] -> bf16 transposed
__global__ __launch_bounds__(256) void cvt_f32_bf16_T(
    const float* __restrict__ in, bf16* __restrict__ out)
{
    __shared__ short tl[32][36];
    const int tid = threadIdx.x;
    const int i = tid >> 3;
    const int j = (tid & 7) * 4;
    const int r0 = blockIdx.x * 32, c0 = blockIdx.y * 32;
    floatx4 v = *(const floatx4*)(in + (size_t)(r0 + i) * 1024 + c0 + j);
#pragma unroll
    for (int p = 0; p < 4; ++p) tl[i][j + p] = f2s(v[p]);
    __syncthreads();
    short4v r;
#pragma unroll
    for (int p = 0; p < 4; ++p) r[p] = tl[j + p][i];
    *(short4v*)(out + (size_t)(c0 + i) * 1024 + r0 + j) = r;
}

// composed bias: out[o] = sum_m w[o,m]*bin[m] + badd[o]
__global__ __launch_bounds__(256) void bias_comp(
    const float* __restrict__ w, const float* __restrict__ bin,
    const float* __restrict__ badd, float* __restrict__ out)
{
    __shared__ float red[4];
    const int o = blockIdx.x;
    const int t = threadIdx.x;
    float s = 0.f;
#pragma unroll
    for (int i = t; i < 1024; i += 256) s += w[(size_t)o * 1024 + i] * bin[i];
#pragma unroll
    for (int off = 32; off >= 1; off >>= 1) s += __shfl_xor(s, off);
    if ((t & 63) == 0) red[t >> 6] = s;
    __syncthreads();
    if (t == 0) out[o] = red[0] + red[1] + red[2] + red[3] + badd[o];
}

// ---------------------------------------------------------------------------
// gemm_bt: legacy 128x128 kernel (kept for the small 1024^3 weight-prep GEMMs)
// ---------------------------------------------------------------------------
template <int RELU>
__global__ __launch_bounds__(256) void gemm_bt(
    const bf16* __restrict__ A, const bf16* __restrict__ W,
    const float* __restrict__ bias, bf16* __restrict__ C,
    int M, int N, int K)
{
    __shared__ __align__(16) short As[16 * 512];
    __shared__ __align__(16) short Ws[16 * 512];

    const int tid  = threadIdx.x;
    const int lane = tid & 63;
    const int wave = tid >> 6;
    const int quad = lane >> 4;
    const int l16  = lane & 15;
    const int r7   = l16 & 7;
    const int bm0  = blockIdx.y * 128;
    const int bn0  = blockIdx.x * 128;
    const int wm   = (wave >> 1) * 64;
    const int wn   = (wave & 1) * 64;

    const int scol = (((lane & 7) ^ (lane >> 3)) * 8);
    const short* Ag = (const short*)A + (size_t)(bm0 + wave * 32 + (lane >> 3)) * K + scol;
    const short* Wg = (const short*)W + (size_t)(bn0 + wave * 32 + (lane >> 3)) * K + scol;
    short* Al = As + (wave * 4) * 512;
    short* Wl = Ws + (wave * 4) * 512;

    floatx4 acc[4][4];
#pragma unroll
    for (int i = 0; i < 4; ++i)
#pragma unroll
        for (int j = 0; j < 4; ++j)
            acc[i][j] = (floatx4){0.f, 0.f, 0.f, 0.f};

    for (int k0 = 0; k0 < K; k0 += 64) {
        __syncthreads();
#pragma unroll
        for (int s = 0; s < 4; ++s) {
            gl_lds16(Ag + k0 + (size_t)s * 8 * K, Al + s * 512);
            gl_lds16(Wg + k0 + (size_t)s * 8 * K, Wl + s * 512);
        }
        __syncthreads();
#pragma unroll
        for (int kk = 0; kk < 64; kk += 32) {
            short8 af[4], bg[4];
#pragma unroll
            for (int i = 0; i < 4; ++i) {
                int row = wm + i * 16 + l16;
                af[i] = *(const short8*)&As[(row >> 3) * 512 + r7 * 64 +
                                            (((quad + (kk >> 3)) ^ r7) << 3)];
            }
#pragma unroll
            for (int j = 0; j < 4; ++j) {
                int row = wn + j * 16 + l16;
                bg[j] = *(const short8*)&Ws[(row >> 3) * 512 + r7 * 64 +
                                            (((quad + (kk >> 3)) ^ r7) << 3)];
            }
#pragma unroll
            for (int i = 0; i < 4; ++i)
#pragma unroll
                for (int j = 0; j < 4; ++j)
                    acc[i][j] = __builtin_amdgcn_mfma_f32_16x16x32_bf16(
                        af[i], bg[j], acc[i][j], 0, 0, 0);
        }
    }

#pragma unroll
    for (int j = 0; j < 4; ++j) {
        int col = bn0 + wn + j * 16 + l16;
        float bv = bias ? bias[col] : 0.f;
#pragma unroll
        for (int i = 0; i < 4; ++i) {
            int row0 = bm0 + wm + i * 16 + quad * 4;
#pragma unroll
            for (int r = 0; r < 4; ++r) {
                float v = acc[i][j][r] + bv;
                if (RELU) v = fmaxf(v, 0.f);
                C[(size_t)(row0 + r) * N + col] = f2b(v);
            }
        }
    }
}

// ---------------------------------------------------------------------------
// gemm256: C = act(A @ W^T + bias), BM=256 x BN=128 x BK=64, 8 waves.
// Triple-buffered LDS, counted vmcnt(6), XOR swizzle, XCD swizzle, setprio.
// ---------------------------------------------------------------------------
template <int RELU>
__global__ __launch_bounds__(512, 2) void gemm256(
    const bf16* __restrict__ A, const bf16* __restrict__ W,
    const float* __restrict__ bias, bf16* __restrict__ C,
    int M, int N, int K)
{
    __shared__ __align__(16) short L[3 * 24576];   // 3 x (A 256x64 + B 128x64)

    const int tid  = threadIdx.x;
    const int lane = tid & 63;
    const int wave = tid >> 6;       // 0..7
    const int quad = lane >> 4;
    const int l16  = lane & 15;
    const int r7   = l16 & 7;
    const int wm   = wave >> 1;      // 0..3  (m-quarter)
    const int wn   = wave & 1;       // 0..1  (n-half)

    const int gx  = gridDim.x;
    const int nwg = gx * gridDim.y;
    int wg = blockIdx.y * gx + blockIdx.x;
    if ((nwg & 7) == 0) wg = (wg & 7) * (nwg >> 3) + (wg >> 3);
    const int bn0 = (wg % gx) * 128;
    const int bm0 = (wg / gx) * 256;

    const int scol = (((lane & 7) ^ ((lane >> 3) & 7)) * 8);
    const short* Ag = (const short*)A + (size_t)(bm0 + wave * 32 + (lane >> 3)) * K + scol;
    const short* Wg = (const short*)W + (size_t)(bn0 + wave * 16 + (lane >> 3)) * K + scol;
    const int aw = (wave * 32) * 64;
    const int bw = 16384 + (wave * 16) * 64;

    floatx4 acc[4][4];
#pragma unroll
    for (int i = 0; i < 4; ++i)
#pragma unroll
        for (int j = 0; j < 4; ++j)
            acc[i][j] = (floatx4){0.f, 0.f, 0.f, 0.f};

    const int T = K / 64;

#pragma unroll
    for (int i = 0; i < 4; ++i) gl_lds16(Ag + (size_t)(i * 8) * K, L + aw + i * 8 * 64);
#pragma unroll
    for (int i = 0; i < 2; ++i) gl_lds16(Wg + (size_t)(i * 8) * K, L + bw + i * 8 * 64);
#pragma unroll
    for (int i = 0; i < 4; ++i) gl_lds16(Ag + 64 + (size_t)(i * 8) * K, L + 24576 + aw + i * 8 * 64);
#pragma unroll
    for (int i = 0; i < 2; ++i) gl_lds16(Wg + 64 + (size_t)(i * 8) * K, L + 24576 + bw + i * 8 * 64);
    asm volatile("s_waitcnt vmcnt(6)" ::: "memory");
    __builtin_amdgcn_s_barrier();

    int cur = 0, stg = 2;
    for (int t = 0; t < T; ++t) {
        __builtin_amdgcn_sched_barrier(0);
        const int kt = (t + 2 < T) ? (t + 2) : (T - 1);
        const size_t kg = (size_t)kt * 64;
        const short* Ac = L + cur * 24576;
        const short* Bc = Ac + 16384;
        short* As_s = L + stg * 24576 + aw;
        short* Bs_s = L + stg * 24576 + bw;

        short8 af[2][2], bf[4][2];

        // phase 0: m-frags 0,1
#pragma unroll
        for (int mi = 0; mi < 2; ++mi)
#pragma unroll
            for (int ks = 0; ks < 2; ++ks)
                af[mi][ks] = *(const short8*)&Ac[(wm * 64 + mi * 16 + l16) * 64 +
                                                (((ks * 4 + quad) ^ r7) << 3)];
#pragma unroll
        for (int nf = 0; nf < 4; ++nf)
#pragma unroll
            for (int ks = 0; ks < 2; ++ks)
                bf[nf][ks] = *(const short8*)&Bc[(wn * 64 + nf * 16 + l16) * 64 +
                                                (((ks * 4 + quad) ^ r7) << 3)];
        gl_lds16(Ag + kg, As_s);
        gl_lds16(Ag + kg + (size_t)8 * K, As_s + 8 * 64);
        gl_lds16(Wg + kg, Bs_s);
        __builtin_amdgcn_s_barrier();
        asm volatile("s_waitcnt lgkmcnt(0)" ::: "memory");
        __builtin_amdgcn_sched_barrier(0);
        __builtin_amdgcn_s_setprio(1);
#pragma unroll
        for (int ks = 0; ks < 2; ++ks)
#pragma unroll
            for (int mi = 0; mi < 2; ++mi)
#pragma unroll
                for (int nf = 0; nf < 4; ++nf)
                    acc[mi][nf] = __builtin_amdgcn_mfma_f32_16x16x32_bf16(
                        af[mi][ks], bf[nf][ks], acc[mi][nf], 0, 0, 0);
        __builtin_amdgcn_s_setprio(0);
        __builtin_amdgcn_s_barrier();

        // phase 1: m-frags 2,3
#pragma unroll
        for (int mi = 0; mi < 2; ++mi)
#pragma unroll
            for (int ks = 0; ks < 2; ++ks)
                af[mi][ks] = *(const short8*)&Ac[(wm * 64 + (2 + mi) * 16 + l16) * 64 +
                                                (((ks * 4 + quad) ^ r7) << 3)];
        gl_lds16(Ag + kg + (size_t)16 * K, As_s + 16 * 64);
        gl_lds16(Ag + kg + (size_t)24 * K, As_s + 24 * 64);
        gl_lds16(Wg + kg + (size_t)8 * K, Bs_s + 8 * 64);
        __builtin_amdgcn_s_barrier();
        asm volatile("s_waitcnt lgkmcnt(0)" ::: "memory");
        __builtin_amdgcn_sched_barrier(0);
        __builtin_amdgcn_s_setprio(1);
#pragma unroll
        for (int ks = 0; ks < 2; ++ks)
#pragma unroll
            for (int mi = 0; mi < 2; ++mi)
#pragma unroll
                for (int nf = 0; nf < 4; ++nf)
                    acc[2 + mi][nf] = __builtin_amdgcn_mfma_f32_16x16x32_bf16(
                        af[mi][ks], bf[nf][ks], acc[2 + mi][nf], 0, 0, 0);
        __builtin_amdgcn_s_setprio(0);
        asm volatile("s_waitcnt vmcnt(6)" ::: "memory");
        __builtin_amdgcn_s_barrier();

        cur = (cur == 2) ? 0 : cur + 1;
        stg = (stg == 2) ? 0 : stg + 1;
    }

#pragma unroll
    for (int nf = 0; nf < 4; ++nf) {
        int col = bn0 + wn * 64 + nf * 16 + l16;
        float bv = bias ? bias[col] : 0.f;
#pragma unroll
        for (int mf = 0; mf < 4; ++mf) {
            int row0 = bm0 + wm * 64 + mf * 16 + quad * 4;
#pragma unroll
            for (int r = 0; r < 4; ++r) {
                float v = acc[mf][nf][r] + bv;
                if (RELU) v = fmaxf(v, 0.f);
                C[(size_t)(row0 + r) * N + col] = f2b(v);
            }
        }
    }
}

// ---------------------------------------------------------------------------
// V transpose: in rows [B*S, str] (head h at col h*128) -> out [B*H][128][S]
// ---------------------------------------------------------------------------
__global__ __launch_bounds__(256) void vtrans(
    const bf16* __restrict__ in, int str, bf16* __restrict__ out, int S)
{
    __shared__ short t[32][36];
    const int tid = threadIdx.x;
    const int s0  = blockIdx.x * 32;
    const int d0  = blockIdx.y * 32;
    const int bh  = blockIdx.z;
    const int b = bh >> 3, h = bh & 7;
    const int i = tid >> 3;
    const int j = (tid & 7) * 4;

    *(short4v*)&t[i][j] =
        *(const short4v*)(in + (size_t)(b * S + s0 + i) * str + h * 128 + d0 + j);
    __syncthreads();
    short4v r;
#pragma unroll
    for (int p = 0; p < 4; ++p) r[p] = t[j + p][i];
    *(short4v*)(out + ((size_t)bh * 128 + d0 + i) * S + s0 + j) = r;
}

// ---------------------------------------------------------------------------
// Flash attention v8:
//  - operand-swapped QK^T + in-register P transpose (cvt_pk + permlane)
//  - CAUSAL: tile-pairing (t, NT-1-t) per block -> perfectly balanced
//    17-chunk blocks (fixes makespan imbalance / 21% occupancy)
//  - T14 async staging: next chunk's K/V loaded global->regs during compute,
//    ds_write after the post-compute barrier (hides HBM latency, LDS stays
//    32 KB).  T5 setprio around the PV MFMA cluster.
// ---------------------------------------------------------------------------
template <int CAUSAL>
__global__ __launch_bounds__(256) void flash_attn(
    const bf16* __restrict__ Q, int qstr, const bf16* __restrict__ K, int kstr,
    const bf16* __restrict__ Vt, const int* __restrict__ pad,
    bf16* __restrict__ Of, float* __restrict__ Ls, int Sq, int Sk)
{
    __shared__ __align__(16) short Ks[64 * 128];   // 16 KB, swizzled
    __shared__ __align__(16) short Vs[128 * 64];   // 16 KB, swizzled

    const int tid  = threadIdx.x;
    const int lane = tid & 63;
    const int wave = tid >> 6;
    const int quad = lane >> 4;
    const int l16  = lane & 15;
    const int r7   = l16 & 7;
    const int bh   = blockIdx.y;
    const int b    = bh >> 3;
    const int h    = bh & 7;
    const int par  = blockIdx.z;

    const int NT = Sq >> 7;
    const float sc = 0.08838834764831845f * 1.4426950408889634f;  // log2 scale
    const bf16* vb0 = Vt + (size_t)bh * 128 * Sk;
    const short* Kb = (const short*)K + (size_t)b * Sk * kstr + h * 128;

    // per-lane staging geometry (constant): seg s -> K row / V row + swizzle col
    int krr[4], kgg[4], vrr[4], vgg[4];
#pragma unroll
    for (int s = 0; s < 4; ++s) {
        int seg = wave * 4 + s;
        krr[s] = seg * 4 + (lane >> 4);
        kgg[s] = (l16 ^ (krr[s] & 7)) * 8;
        vrr[s] = seg * 8 + (lane >> 3);
        vgg[s] = ((lane & 7) ^ (vrr[s] & 7)) * 8;
    }

    const int npass = CAUSAL ? 2 : 1;
    for (int ps = 0; ps < npass; ++ps) {
        const int tile = CAUSAL ? (ps ? NT - 1 - (int)blockIdx.x : (int)blockIdx.x)
                                : (int)blockIdx.x;
        const int q0 = tile * 128;
        const int qw = q0 + wave * 32;

        short8 qf[2][4];
#pragma unroll
        for (int mi = 0; mi < 2; ++mi) {
            const bf16* qb = Q + (size_t)(b * Sq + qw + mi * 16 + l16) * qstr + h * 128;
#pragma unroll
            for (int c = 0; c < 4; ++c)
                qf[mi][c] = *(const short8*)(qb + c * 32 + quad * 8);
        }

        floatx4 o[2][8];
#pragma unroll
        for (int mi = 0; mi < 2; ++mi)
#pragma unroll
            for (int nf = 0; nf < 8; ++nf) o[mi][nf] = (floatx4){0.f, 0.f, 0.f, 0.f};
        float lsum[2] = {0.f, 0.f};

        int kEnd = Sk;
        if (CAUSAL && q0 + 128 < Sk) kEnd = q0 + 128;

        // prologue: stage first chunk into regs
        intx4 sk[4], sv[4];
        {
            const int kc = par * 64;
#pragma unroll
            for (int s = 0; s < 4; ++s) {
                sk[s] = *(const intx4*)(Kb + (size_t)(kc + krr[s]) * kstr + kgg[s]);
                sv[s] = *(const intx4*)((const short*)vb0 + (size_t)vrr[s] * Sk + kc + vgg[s]);
            }
        }

        for (int ci = par; ci * 64 < kEnd; ci += 2) {
            const int kc = ci * 64;
            __syncthreads();                 // all waves done reading prev chunk LDS
#pragma unroll
            for (int s = 0; s < 4; ++s) {    // compiler inserts vmcnt wait before use
                *(intx4*)&Ks[(wave * 4 + s) * 512 + lane * 8] = sk[s];
                *(intx4*)&Vs[(wave * 4 + s) * 512 + lane * 8] = sv[s];
            }
            __syncthreads();                 // staged data visible

            const int kcn = kc + 128;
            if (kcn < kEnd) {                // issue next chunk's loads early
#pragma unroll
                for (int s = 0; s < 4; ++s) {
                    sk[s] = *(const intx4*)(Kb + (size_t)(kcn + krr[s]) * kstr + kgg[s]);
                    sv[s] = *(const intx4*)((const short*)vb0 + (size_t)vrr[s] * Sk + kcn + vgg[s]);
                }
            }
            __builtin_amdgcn_sched_barrier(0);   // pin loads before compute

            short8 pfm[2][2];
#pragma unroll
            for (int c = 0; c < 2; ++c) {
                floatx4 sT[2][2];
#pragma unroll
                for (int fp = 0; fp < 2; ++fp) {
                    const int f = c * 2 + fp;
                    const int krow = f * 16 + l16;
                    short8 kf[4];
#pragma unroll
                    for (int cc = 0; cc < 4; ++cc)
                        kf[cc] = *(const short8*)&Ks[krow * 128 + (((cc * 4 + quad) ^ r7) << 3)];
#pragma unroll
                    for (int mi = 0; mi < 2; ++mi) {
                        floatx4 s = (floatx4){0.f, 0.f, 0.f, 0.f};
#pragma unroll
                        for (int cc = 0; cc < 4; ++cc)
                            s = __builtin_amdgcn_mfma_f32_16x16x32_bf16(
                                kf[cc], qf[mi][cc], s, 0, 0, 0);
                        sT[mi][fp] = s;
                    }
                }

                const int* pb = pad + (size_t)b * Sk + kc + c * 32 + quad * 4;
                intx4 pv0 = *(const intx4*)pb;
                intx4 pv1 = *(const intx4*)(pb + 16);

#pragma unroll
                for (int mi = 0; mi < 2; ++mi) {
                    const int qv = qw + mi * 16 + l16;
#pragma unroll
                    for (int fp = 0; fp < 2; ++fp) {
#pragma unroll
                        for (int r = 0; r < 4; ++r) {
                            int kk = kc + (c * 2 + fp) * 16 + quad * 4 + r;
                            bool ok = ((fp ? pv1[r] : pv0[r]) != 0);
                            if (CAUSAL) ok = ok && (kk <= qv);
                            float p = ok ? __builtin_amdgcn_exp2f(sT[mi][fp][r] * sc) : 0.f;
                            sT[mi][fp][r] = p;
                            lsum[mi] += p;
                        }
                    }
                    unsigned wA = cvtpk_bf16(sT[mi][0][0], sT[mi][0][1]);
                    unsigned wB = cvtpk_bf16(sT[mi][0][2], sT[mi][0][3]);
                    unsigned wC = cvtpk_bf16(sT[mi][1][0], sT[mi][1][1]);
                    unsigned wD = cvtpk_bf16(sT[mi][1][2], sT[mi][1][3]);
                    pl32swap(wA, wC);
                    pl16swap(wA, wC);
                    pl32swap(wB, wD);
                    pl16swap(wB, wD);
                    uintx4 t;
                    t[0] = wA; t[1] = wB; t[2] = wC; t[3] = wD;
                    pfm[mi][c] = __builtin_bit_cast(short8, t);
                }
            }

            __builtin_amdgcn_s_setprio(1);
#pragma unroll
            for (int nf = 0; nf < 8; ++nf) {
                int vrow = nf * 16 + l16;
                short8 vf0 = *(const short8*)&Vs[vrow * 64 + ((quad ^ r7) << 3)];
                short8 vf1 = *(const short8*)&Vs[vrow * 64 + (((4 + quad) ^ r7) << 3)];
#pragma unroll
                for (int mi = 0; mi < 2; ++mi) {
                    o[mi][nf] = __builtin_amdgcn_mfma_f32_16x16x32_bf16(
                        pfm[mi][0], vf0, o[mi][nf], 0, 0, 0);
                    o[mi][nf] = __builtin_amdgcn_mfma_f32_16x16x32_bf16(
                        pfm[mi][1], vf1, o[mi][nf], 0, 0, 0);
                }
            }
            __builtin_amdgcn_s_setprio(0);
        }

        // write unnormalized O (bf16) + row sums for this split
        bf16* op = Of + (size_t)par * B_ * Sq * DM_;
        float* lp = Ls + (size_t)par * B_ * H_ * Sq;
#pragma unroll
        for (int mi = 0; mi < 2; ++mi) {
            float s = lsum[mi];
            s += __shfl_xor(s, 16);
            s += __shfl_xor(s, 32);
            if (lane < 16)
                lp[(size_t)bh * Sq + qw + mi * 16 + l16] = s;
#pragma unroll
            for (int nf = 0; nf < 8; ++nf)
#pragma unroll
                for (int r = 0; r < 4; ++r) {
                    int q = qw + mi * 16 + quad * 4 + r;
                    op[(size_t)(b * Sq + q) * DM_ + h * 128 + nf * 16 + l16] =
                        f2b(o[mi][nf][r]);
                }
        }
    }
}

// combine: out = (O0 + O1) / (L0 + L1)
__global__ __launch_bounds__(256) void attn_combine(
    const bf16* __restrict__ Of, const float* __restrict__ Ls,
    bf16* __restrict__ out)
{
    const int row = blockIdx.x;           // b*SD_+q
    const int t = threadIdx.x;
    const int col = t * 4;
    const int h = col >> 7;
    const int b = row >> 11;
    const int q = row & (SD_ - 1);
    const size_t NV = (size_t)B_ * SD_ * DM_;
    const int idx = (b * H_ + h) * SD_ + q;
    float l = Ls[idx] + Ls[B_ * H_ * SD_ + idx];
    float inv = l > 0.f ? 1.f / l : 0.f;
    size_t base = (size_t)row * DM_ + col;
    short4v a0 = *(const short4v*)(Of + base);
    short4v a1 = *(const short4v*)(Of + NV + base);
    short4v r;
#pragma unroll
    for (int i = 0; i < 4; ++i)
        r[i] = f2s((b2f(__builtin_bit_cast(bf16, (short)a0[i])) +
                    b2f(__builtin_bit_cast(bf16, (short)a1[i]))) * inv);
    *(short4v*)(out + base) = r;
}

// ---------------------------------------------------------------------------
// out = LayerNorm(a + b) * g + beta
// ---------------------------------------------------------------------------
template <int A32, int O32>
__global__ __launch_bounds__(256) void add_ln(
    const void* __restrict__ Ap, const bf16* __restrict__ Bv,
    const float* __restrict__ g, const float* __restrict__ be,
    void* __restrict__ outp)
{
    const int D = DM_;
    __shared__ float red[8];
    const size_t row = blockIdx.x;
    const int t = threadIdx.x;

    float x[4];
    {
        float av[4];
        if (A32) {
            floatx4 a4 = *(const floatx4*)((const float*)Ap + row * D + t * 4);
#pragma unroll
            for (int i = 0; i < 4; ++i) av[i] = a4[i];
        } else {
            short4v a4 = *(const short4v*)((const bf16*)Ap + row * D + t * 4);
#pragma unroll
            for (int i = 0; i < 4; ++i)
                av[i] = b2f(__builtin_bit_cast(bf16, (short)a4[i]));
        }
        short4v b4 = *(const short4v*)(Bv + row * D + t * 4);
#pragma unroll
        for (int i = 0; i < 4; ++i)
            x[i] = av[i] + b2f(__builtin_bit_cast(bf16, (short)b4[i]));
    }
    float s = 0.f, s2 = 0.f;
#pragma unroll
    for (int i = 0; i < 4; ++i) { s += x[i]; s2 += x[i] * x[i]; }
#pragma unroll
    for (int off = 32; off >= 1; off >>= 1) {
        s  += __shfl_xor(s, off);
        s2 += __shfl_xor(s2, off);
    }
    const int wave = t >> 6;
    if ((t & 63) == 0) { red[wave] = s; red[4 + wave] = s2; }
    __syncthreads();
    s  = red[0] + red[1] + red[2] + red[3];
    s2 = red[4] + red[5] + red[6] + red[7];
    const float mu   = s * (1.f / D);
    const float var  = s2 * (1.f / D) - mu * mu;
    const float rstd = rsqrtf(var + 1e-5f);
#pragma unroll
    for (int i = 0; i < 4; ++i) {
        int idx = t * 4 + i;
        float v = (x[i] - mu) * rstd * g[idx] + be[idx];
        if (O32) ((float*)outp)[row * D + idx] = v;
        else     ((bf16*)outp)[row * D + idx] = f2b(v);
    }
}

// ---------------------------------------------------------------------------
extern "C" void kernel_launch(void* const* d_in, const int* in_sizes, int n_in,
                              void* d_out, int out_size, void* d_ws, size_t ws_size,
                              hipStream_t stream)
{
    const float* emb    = (const float*)d_in[0];
    const float* enc    = (const float*)d_in[1];
    const int*  in_pad  = (const int*)d_in[2];
    const int*  out_pad = (const int*)d_in[3];
    const float* q1_w = (const float*)d_in[4];  const float* q1_b = (const float*)d_in[5];
    const float* k1_w = (const float*)d_in[6];  const float* k1_b = (const float*)d_in[7];
    const float* v1_w = (const float*)d_in[8];  const float* v1_b = (const float*)d_in[9];
    const float* q2_w = (const float*)d_in[10]; const float* q2_b = (const float*)d_in[11];
    const float* k2_w = (const float*)d_in[12]; const float* k2_b = (const float*)d_in[13];
    const float* v2_w = (const float*)d_in[14]; const float* v2_b = (const float*)d_in[15];
    const float* sa_qw = (const float*)d_in[16]; const float* sa_qb = (const float*)d_in[17];
    const float* sa_kw = (const float*)d_in[18]; const float* sa_kb = (const float*)d_in[19];
    const float* sa_vw = (const float*)d_in[20]; const float* sa_vb = (const float*)d_in[21];
    const float* sa_ow = (const float*)d_in[22]; const float* sa_ob = (const float*)d_in[23];
    const float* ed_qw = (const float*)d_in[24]; const float* ed_qb = (const float*)d_in[25];
    const float* ed_kw = (const float*)d_in[26]; const float* ed_kb = (const float*)d_in[27];
    const float* ed_vw = (const float*)d_in[28]; const float* ed_vb = (const float*)d_in[29];
    const float* ed_ow = (const float*)d_in[30]; const float* ed_ob = (const float*)d_in[31];
    const float* ff_w1 = (const float*)d_in[32]; const float* ff_b1 = (const float*)d_in[33];
    const float* ff_w2 = (const float*)d_in[34]; const float* ff_b2 = (const float*)d_in[35];
    const float* ln1_g = (const float*)d_in[36]; const float* ln1_b = (const float*)d_in[37];
    const float* ln2_g = (const float*)d_in[38]; const float* ln2_b = (const float*)d_in[39];

    const int M = B_ * SD_;                 // 8192
    const size_t MM = (size_t)1024 * 1024;
    bf16* ws = (bf16*)d_ws;

    // ---- workspace layout (bf16 units) ----
    bf16* Wqkv = ws;                 // [3072,1024]
    bf16* Wkv  = ws + 3 * MM;        // [2048,1024]
    bf16* Wq2  = ws + 5 * MM;
    bf16* Wso  = ws + 6 * MM;
    bf16* Weo  = ws + 7 * MM;
    bf16* Wf1  = ws + 8 * MM;
    bf16* Wf2  = ws + 12 * MM;
    float* bQKV = (float*)(ws + 16 * MM);          // 3072 f
    float* bKV  = bQKV + 3072;                     // 2048 f
    float* bQ2  = bKV + 2048;                      // 1024 f
    float* Lsum = bQ2 + 2048;                      // 2*32*2048 f = 512 KB
    bf16* hw   = ws + 17 * MM;
    bf16* ft   = ws + 23 * MM;
    bf16* emb_b = ws + 17 * MM;      // 8M (after composes)
    bf16* enc_b = ws + 25 * MM;      // 8M
    bf16* sqkv  = ws + 33 * MM;      // 24M [8192,3072]
    bf16* skv   = ws + 33 * MM;      // 16M [8192,2048] (after flash1)
    bf16* sq2   = ws + 49 * MM;      // 8M
    bf16* sVt   = ws + 57 * MM;      // 8M  [32][128][2048]
    bf16* attn  = ws + 65 * MM;      // 8M
    bf16* Ofb   = ws + 73 * MM;      // 16M (2 splits x 8M, unnormalized O)
    bf16* s1    = ws + 73 * MM;      // 8M (reused after combine)
    bf16* x     = ws + 89 * MM;      // 8M
    bf16* y     = ws + 33 * MM;      // 8M (after flash2)
    bf16* mid   = ws + 41 * MM;      // 32M
    bf16* f2    = ws + 81 * MM;      // 8M

    // main GEMMs: 256x128-tile pipelined kernel
    auto G = [&](const bf16* Ai, const bf16* Wi, const float* bi, bf16* Ci,
                 int Mi, int Ni, int Ki, bool relu) {
        dim3 grid(Ni / 128, Mi / 256);
        if (relu) gemm256<1><<<grid, 512, 0, stream>>>(Ai, Wi, bi, Ci, Mi, Ni, Ki);
        else      gemm256<0><<<grid, 512, 0, stream>>>(Ai, Wi, bi, Ci, Mi, Ni, Ki);
    };
    // weight-prep GEMMs (1024^3): legacy 128x128 kernel (better grid fill)
    auto Gp = [&](const bf16* Ai, const bf16* Wi, bf16* Ci) {
        dim3 grid(8, 8);
        gemm_bt<0><<<grid, 256, 0, stream>>>(Ai, Wi, nullptr, Ci, 1024, 1024, 1024);
    };

    // ---- weight preparation ----
    const float* hsrc[6] = {sa_qw, sa_kw, sa_vw, ed_qw, ed_kw, ed_vw};
    for (int i = 0; i < 6; ++i)
        cvt_f32_bf16<<<dim3(MM / 2048), 256, 0, stream>>>(hsrc[i], hw + i * MM, (int)MM);
    const float* tsrc[6] = {q1_w, k1_w, v1_w, q2_w, k2_w, v2_w};
    for (int i = 0; i < 6; ++i)
        cvt_f32_bf16_T<<<dim3(32, 32), 256, 0, stream>>>(tsrc[i], ft + i * MM);
    bias_comp<<<dim3(1024), 256, 0, stream>>>(sa_qw, q1_b, sa_qb, bQKV);
    bias_comp<<<dim3(1024), 256, 0, stream>>>(sa_kw, k1_b, sa_kb, bQKV + 1024);
    bias_comp<<<dim3(1024), 256, 0, stream>>>(sa_vw, v1_b, sa_vb, bQKV + 2048);
    bias_comp<<<dim3(1024), 256, 0, stream>>>(ed_kw, k2_b, ed_kb, bKV);
    bias_comp<<<dim3(1024), 256, 0, stream>>>(ed_vw, v2_b, ed_vb, bKV + 1024);
    bias_comp<<<dim3(1024), 256, 0, stream>>>(ed_qw, q2_b, ed_qb, bQ2);
    Gp(hw + 0 * MM, ft + 0 * MM, Wqkv + 0 * MM);
    Gp(hw + 1 * MM, ft + 1 * MM, Wqkv + 1 * MM);
    Gp(hw + 2 * MM, ft + 2 * MM, Wqkv + 2 * MM);
    Gp(hw + 4 * MM, ft + 4 * MM, Wkv  + 0 * MM);
    Gp(hw + 5 * MM, ft + 5 * MM, Wkv  + 1 * MM);
    Gp(hw + 3 * MM, ft + 3 * MM, Wq2);
    cvt_f32_bf16<<<dim3(MM / 2048), 256, 0, stream>>>(sa_ow, Wso, (int)MM);
    cvt_f32_bf16<<<dim3(MM / 2048), 256, 0, stream>>>(ed_ow, Weo, (int)MM);
    cvt_f32_bf16<<<dim3(4 * MM / 2048), 256, 0, stream>>>(ff_w1, Wf1, (int)(4 * MM));
    cvt_f32_bf16<<<dim3(4 * MM / 2048), 256, 0, stream>>>(ff_w2, Wf2, (int)(4 * MM));
    cvt_f32_bf16<<<dim3(8 * MM / 2048), 256, 0, stream>>>(emb, emb_b, (int)(8 * MM));
    cvt_f32_bf16<<<dim3(8 * MM / 2048), 256, 0, stream>>>(enc, enc_b, (int)(8 * MM));

    // ---- self attention ----
    G(emb_b, Wqkv, bQKV, sqkv, M, 3072, DM_, false);          // Qh|Kh|Vh
    vtrans<<<dim3(SD_ / 32, 4, B_ * H_), 256, 0, stream>>>(sqkv + 2048, 3072, sVt, SD_);
    flash_attn<1><<<dim3(SD_ / 256, B_ * H_, 2), 256, 0, stream>>>(
        sqkv, 3072, sqkv + 1024, 3072, sVt, out_pad, Ofb, Lsum, SD_, SD_);
    attn_combine<<<dim3(M), 256, 0, stream>>>(Ofb, Lsum, attn);
    G(attn, Wso, sa_ob, s1, M, DM_, DM_, false);
    add_ln<1, 0><<<dim3(M), 256, 0, stream>>>(emb, s1, ln1_g, ln1_b, x);

    // ---- cross attention (residual from emb, per reference) ----
    G(enc_b, Wkv, bKV, skv, M, 2048, DM_, false);             // Kh2|Vh2
    G(x, Wq2, bQ2, sq2, M, DM_, DM_, false);                  // Qh2
    vtrans<<<dim3(SE_ / 32, 4, B_ * H_), 256, 0, stream>>>(skv + 1024, 2048, sVt, SE_);
    flash_attn<0><<<dim3(SD_ / 128, B_ * H_, 2), 256, 0, stream>>>(
        sq2, 1024, skv, 2048, sVt, in_pad, Ofb, Lsum, SD_, SE_);
    attn_combine<<<dim3(M), 256, 0, stream>>>(Ofb, Lsum, attn);
    G(attn, Weo, ed_ob, s1, M, DM_, DM_, false);
    add_ln<1, 0><<<dim3(M), 256, 0, stream>>>(emb, s1, ln2_g, ln2_b, y);

    // ---- FFN (final norm reuses ln2 params, per reference) ----
    G(y, Wf1, ff_b1, mid, M, DFF_, DM_, true);
    G(mid, Wf2, ff_b2, f2, M, DM_, DFF_, false);
    add_ln<0, 1><<<dim3(M), 256, 0, stream>>>(y, f2, ln2_g, ln2_b, d_out);
}

// Round 6
// 859.824 us; speedup vs baseline: 1.2738x; 1.1640x over previous
//
#include <hip/hip_runtime.h>
#include <hip/hip_bf16.h>

typedef __hip_bfloat16 bf16;
typedef short short8 __attribute__((ext_vector_type(8)));
typedef short short4v __attribute__((ext_vector_type(4)));
typedef float floatx4 __attribute__((ext_vector_type(4)));
typedef int intx4 __attribute__((ext_vector_type(4)));
typedef unsigned int uintx4 __attribute__((ext_vector_type(4)));

#define B_ 4
#define SD_ 2048
#define SE_ 2048
#define DM_ 1024
#define H_ 8
#define DFF_ 4096

struct PtrsIn  { const void* p[6]; };
struct PtrsOut { void* p[6]; };
struct Int6    { int v[6]; };

__device__ __forceinline__ float b2f(bf16 v) { return __bfloat162float(v); }
__device__ __forceinline__ bf16 f2b(float v) { return __float2bfloat16(v); }
__device__ __forceinline__ short f2s(float v) { return __builtin_bit_cast(short, __float2bfloat16(v)); }

// pack two f32 -> one u32 of 2x bf16 (lo = first arg)
__device__ __forceinline__ unsigned cvtpk_bf16(float lo, float hi) {
    unsigned r;
    asm("v_cvt_pk_bf16_f32 %0, %1, %2" : "=v"(r) : "v"(lo), "v"(hi));
    return r;
}
__device__ __forceinline__ void pl32swap(unsigned &x, unsigned &y) {
    asm("v_permlane32_swap_b32 %0, %1" : "+v"(x), "+v"(y));
}
__device__ __forceinline__ void pl16swap(unsigned &x, unsigned &y) {
    asm("v_permlane16_swap_b32 %0, %1" : "+v"(x), "+v"(y));
}

// async global->LDS, 16B/lane. LDS dest = wave-uniform base + lane*16.
__device__ __forceinline__ void gl_lds16(const short* g, short* l) {
    __builtin_amdgcn_global_load_lds(
        (const __attribute__((address_space(1))) void*)g,
        (__attribute__((address_space(3))) void*)l, 16, 0, 0);
}

// ---------------------------------------------------------------------------
// batched f32->bf16 convert: segment y, per-segment element count n.v[y]
// ---------------------------------------------------------------------------
__global__ __launch_bounds__(256) void cvt6(PtrsIn in, PtrsOut out, Int6 n)
{
    const int y = blockIdx.y;
    int i = (blockIdx.x * 256 + threadIdx.x) * 8;
    if (i >= n.v[y]) return;
    const float* src = (const float*)in.p[y];
    bf16* dst = (bf16*)out.p[y];
    floatx4 a = *(const floatx4*)(src + i);
    floatx4 b = *(const floatx4*)(src + i + 4);
    short8 r;
#pragma unroll
    for (int k = 0; k < 4; ++k) { r[k] = f2s(a[k]); r[k + 4] = f2s(b[k]); }
    *(short8*)(dst + i) = r;
}

// batched fp32 [1024,1024] -> bf16 transposed (segment z -> out + z*1M)
__global__ __launch_bounds__(256) void cvtT6(PtrsIn in, bf16* out)
{
    __shared__ short tl[32][36];
    const int z = blockIdx.z;
    const float* src = (const float*)in.p[z];
    bf16* dst = out + (size_t)z * 1024 * 1024;
    const int tid = threadIdx.x;
    const int i = tid >> 3;
    const int j = (tid & 7) * 4;
    const int r0 = blockIdx.x * 32, c0 = blockIdx.y * 32;
    floatx4 v = *(const floatx4*)(src + (size_t)(r0 + i) * 1024 + c0 + j);
#pragma unroll
    for (int p = 0; p < 4; ++p) tl[i][j + p] = f2s(v[p]);
    __syncthreads();
    short4v r;
#pragma unroll
    for (int p = 0; p < 4; ++p) r[p] = tl[j + p][i];
    *(short4v*)(dst + (size_t)(c0 + i) * 1024 + r0 + j) = r;
}

// batched composed bias: segment y: out[o] = sum_m w[o,m]*bin[m] + badd[o]
__global__ __launch_bounds__(256) void bias6(
    PtrsIn w6, PtrsIn bin6, PtrsIn badd6, PtrsOut out6)
{
    __shared__ float red[4];
    const int y = blockIdx.y;
    const float* w    = (const float*)w6.p[y];
    const float* bin  = (const float*)bin6.p[y];
    const float* badd = (const float*)badd6.p[y];
    float* out        = (float*)out6.p[y];
    const int o = blockIdx.x;
    const int t = threadIdx.x;
    float s = 0.f;
#pragma unroll
    for (int i = t; i < 1024; i += 256) s += w[(size_t)o * 1024 + i] * bin[i];
#pragma unroll
    for (int off = 32; off >= 1; off >>= 1) s += __shfl_xor(s, off);
    if ((t & 63) == 0) red[t >> 6] = s;
    __syncthreads();
    if (t == 0) out[o] = red[0] + red[1] + red[2] + red[3] + badd[o];
}

// ---------------------------------------------------------------------------
// gemm_prep: batched 1024^3 weight-compose GEMMs (z selects problem).
// 128x128 tile, gl_lds staging with XOR swizzle (legacy gemm_bt body).
// ---------------------------------------------------------------------------
__global__ __launch_bounds__(256) void gemm_prep(PtrsIn A6, PtrsIn W6, PtrsOut C6)
{
    __shared__ __align__(16) short As[16 * 512];
    __shared__ __align__(16) short Ws[16 * 512];

    const int K = 1024, N = 1024;
    const int z = blockIdx.z;
    const bf16* A = (const bf16*)A6.p[z];
    const bf16* W = (const bf16*)W6.p[z];
    bf16* C = (bf16*)C6.p[z];

    const int tid  = threadIdx.x;
    const int lane = tid & 63;
    const int wave = tid >> 6;
    const int quad = lane >> 4;
    const int l16  = lane & 15;
    const int r7   = l16 & 7;
    const int bm0  = blockIdx.y * 128;
    const int bn0  = blockIdx.x * 128;
    const int wm   = (wave >> 1) * 64;
    const int wn   = (wave & 1) * 64;

    const int scol = (((lane & 7) ^ (lane >> 3)) * 8);
    const short* Ag = (const short*)A + (size_t)(bm0 + wave * 32 + (lane >> 3)) * K + scol;
    const short* Wg = (const short*)W + (size_t)(bn0 + wave * 32 + (lane >> 3)) * K + scol;
    short* Al = As + (wave * 4) * 512;
    short* Wl = Ws + (wave * 4) * 512;

    floatx4 acc[4][4];
#pragma unroll
    for (int i = 0; i < 4; ++i)
#pragma unroll
        for (int j = 0; j < 4; ++j)
            acc[i][j] = (floatx4){0.f, 0.f, 0.f, 0.f};

    for (int k0 = 0; k0 < K; k0 += 64) {
        __syncthreads();
#pragma unroll
        for (int s = 0; s < 4; ++s) {
            gl_lds16(Ag + k0 + (size_t)s * 8 * K, Al + s * 512);
            gl_lds16(Wg + k0 + (size_t)s * 8 * K, Wl + s * 512);
        }
        __syncthreads();
#pragma unroll
        for (int kk = 0; kk < 64; kk += 32) {
            short8 af[4], bg[4];
#pragma unroll
            for (int i = 0; i < 4; ++i) {
                int row = wm + i * 16 + l16;
                af[i] = *(const short8*)&As[(row >> 3) * 512 + r7 * 64 +
                                            (((quad + (kk >> 3)) ^ r7) << 3)];
            }
#pragma unroll
            for (int j = 0; j < 4; ++j) {
                int row = wn + j * 16 + l16;
                bg[j] = *(const short8*)&Ws[(row >> 3) * 512 + r7 * 64 +
                                            (((quad + (kk >> 3)) ^ r7) << 3)];
            }
#pragma unroll
            for (int i = 0; i < 4; ++i)
#pragma unroll
                for (int j = 0; j < 4; ++j)
                    acc[i][j] = __builtin_amdgcn_mfma_f32_16x16x32_bf16(
                        af[i], bg[j], acc[i][j], 0, 0, 0);
        }
    }

#pragma unroll
    for (int j = 0; j < 4; ++j) {
        int col = bn0 + wn + j * 16 + l16;
#pragma unroll
        for (int i = 0; i < 4; ++i) {
            int row0 = bm0 + wm + i * 16 + quad * 4;
#pragma unroll
            for (int r = 0; r < 4; ++r)
                C[(size_t)(row0 + r) * N + col] = f2b(acc[i][j][r]);
        }
    }
}

// ---------------------------------------------------------------------------
// gemm256: C = act(A @ W^T + bias), BM=256 x BN=128 x BK=64, 8 waves.
// Triple-buffered LDS, counted vmcnt(6), XOR swizzle, XCD swizzle, setprio.
// ---------------------------------------------------------------------------
template <int RELU>
__global__ __launch_bounds__(512, 2) void gemm256(
    const bf16* __restrict__ A, const bf16* __restrict__ W,
    const float* __restrict__ bias, bf16* __restrict__ C,
    int M, int N, int K)
{
    __shared__ __align__(16) short L[3 * 24576];   // 3 x (A 256x64 + B 128x64)

    const int tid  = threadIdx.x;
    const int lane = tid & 63;
    const int wave = tid >> 6;       // 0..7
    const int quad = lane >> 4;
    const int l16  = lane & 15;
    const int r7   = l16 & 7;
    const int wm   = wave >> 1;      // 0..3  (m-quarter)
    const int wn   = wave & 1;       // 0..1  (n-half)

    const int gx  = gridDim.x;
    const int nwg = gx * gridDim.y;
    int wg = blockIdx.y * gx + blockIdx.x;
    if ((nwg & 7) == 0) wg = (wg & 7) * (nwg >> 3) + (wg >> 3);
    const int bn0 = (wg % gx) * 128;
    const int bm0 = (wg / gx) * 256;

    const int scol = (((lane & 7) ^ ((lane >> 3) & 7)) * 8);
    const short* Ag = (const short*)A + (size_t)(bm0 + wave * 32 + (lane >> 3)) * K + scol;
    const short* Wg = (const short*)W + (size_t)(bn0 + wave * 16 + (lane >> 3)) * K + scol;
    const int aw = (wave * 32) * 64;
    const int bw = 16384 + (wave * 16) * 64;

    floatx4 acc[4][4];
#pragma unroll
    for (int i = 0; i < 4; ++i)
#pragma unroll
        for (int j = 0; j < 4; ++j)
            acc[i][j] = (floatx4){0.f, 0.f, 0.f, 0.f};

    const int T = K / 64;

#pragma unroll
    for (int i = 0; i < 4; ++i) gl_lds16(Ag + (size_t)(i * 8) * K, L + aw + i * 8 * 64);
#pragma unroll
    for (int i = 0; i < 2; ++i) gl_lds16(Wg + (size_t)(i * 8) * K, L + bw + i * 8 * 64);
#pragma unroll
    for (int i = 0; i < 4; ++i) gl_lds16(Ag + 64 + (size_t)(i * 8) * K, L + 24576 + aw + i * 8 * 64);
#pragma unroll
    for (int i = 0; i < 2; ++i) gl_lds16(Wg + 64 + (size_t)(i * 8) * K, L + 24576 + bw + i * 8 * 64);
    asm volatile("s_waitcnt vmcnt(6)" ::: "memory");
    __builtin_amdgcn_s_barrier();

    int cur = 0, stg = 2;
    for (int t = 0; t < T; ++t) {
        __builtin_amdgcn_sched_barrier(0);
        const int kt = (t + 2 < T) ? (t + 2) : (T - 1);
        const size_t kg = (size_t)kt * 64;
        const short* Ac = L + cur * 24576;
        const short* Bc = Ac + 16384;
        short* As_s = L + stg * 24576 + aw;
        short* Bs_s = L + stg * 24576 + bw;

        short8 af[2][2], bf[4][2];

        // phase 0: m-frags 0,1
#pragma unroll
        for (int mi = 0; mi < 2; ++mi)
#pragma unroll
            for (int ks = 0; ks < 2; ++ks)
                af[mi][ks] = *(const short8*)&Ac[(wm * 64 + mi * 16 + l16) * 64 +
                                                (((ks * 4 + quad) ^ r7) << 3)];
#pragma unroll
        for (int nf = 0; nf < 4; ++nf)
#pragma unroll
            for (int ks = 0; ks < 2; ++ks)
                bf[nf][ks] = *(const short8*)&Bc[(wn * 64 + nf * 16 + l16) * 64 +
                                                (((ks * 4 + quad) ^ r7) << 3)];
        gl_lds16(Ag + kg, As_s);
        gl_lds16(Ag + kg + (size_t)8 * K, As_s + 8 * 64);
        gl_lds16(Wg + kg, Bs_s);
        __builtin_amdgcn_s_barrier();
        asm volatile("s_waitcnt lgkmcnt(0)" ::: "memory");
        __builtin_amdgcn_sched_barrier(0);
        __builtin_amdgcn_s_setprio(1);
#pragma unroll
        for (int ks = 0; ks < 2; ++ks)
#pragma unroll
            for (int mi = 0; mi < 2; ++mi)
#pragma unroll
                for (int nf = 0; nf < 4; ++nf)
                    acc[mi][nf] = __builtin_amdgcn_mfma_f32_16x16x32_bf16(
                        af[mi][ks], bf[nf][ks], acc[mi][nf], 0, 0, 0);
        __builtin_amdgcn_s_setprio(0);
        __builtin_amdgcn_s_barrier();

        // phase 1: m-frags 2,3
#pragma unroll
        for (int mi = 0; mi < 2; ++mi)
#pragma unroll
            for (int ks = 0; ks < 2; ++ks)
                af[mi][ks] = *(const short8*)&Ac[(wm * 64 + (2 + mi) * 16 + l16) * 64 +
                                                (((ks * 4 + quad) ^ r7) << 3)];
        gl_lds16(Ag + kg + (size_t)16 * K, As_s + 16 * 64);
        gl_lds16(Ag + kg + (size_t)24 * K, As_s + 24 * 64);
        gl_lds16(Wg + kg + (size_t)8 * K, Bs_s + 8 * 64);
        __builtin_amdgcn_s_barrier();
        asm volatile("s_waitcnt lgkmcnt(0)" ::: "memory");
        __builtin_amdgcn_sched_barrier(0);
        __builtin_amdgcn_s_setprio(1);
#pragma unroll
        for (int ks = 0; ks < 2; ++ks)
#pragma unroll
            for (int mi = 0; mi < 2; ++mi)
#pragma unroll
                for (int nf = 0; nf < 4; ++nf)
                    acc[2 + mi][nf] = __builtin_amdgcn_mfma_f32_16x16x32_bf16(
                        af[mi][ks], bf[nf][ks], acc[2 + mi][nf], 0, 0, 0);
        __builtin_amdgcn_s_setprio(0);
        asm volatile("s_waitcnt vmcnt(6)" ::: "memory");
        __builtin_amdgcn_s_barrier();

        cur = (cur == 2) ? 0 : cur + 1;
        stg = (stg == 2) ? 0 : stg + 1;
    }

#pragma unroll
    for (int nf = 0; nf < 4; ++nf) {
        int col = bn0 + wn * 64 + nf * 16 + l16;
        float bv = bias ? bias[col] : 0.f;
#pragma unroll
        for (int mf = 0; mf < 4; ++mf) {
            int row0 = bm0 + wm * 64 + mf * 16 + quad * 4;
#pragma unroll
            for (int r = 0; r < 4; ++r) {
                float v = acc[mf][nf][r] + bv;
                if (RELU) v = fmaxf(v, 0.f);
                C[(size_t)(row0 + r) * N + col] = f2b(v);
            }
        }
    }
}

// ---------------------------------------------------------------------------
// V transpose: in rows [B*S, str] (head h at col h*128) -> out [B*H][128][S]
// ---------------------------------------------------------------------------
__global__ __launch_bounds__(256) void vtrans(
    const bf16* __restrict__ in, int str, bf16* __restrict__ out, int S)
{
    __shared__ short t[32][36];
    const int tid = threadIdx.x;
    const int s0  = blockIdx.x * 32;
    const int d0  = blockIdx.y * 32;
    const int bh  = blockIdx.z;
    const int b = bh >> 3, h = bh & 7;
    const int i = tid >> 3;
    const int j = (tid & 7) * 4;

    *(short4v*)&t[i][j] =
        *(const short4v*)(in + (size_t)(b * S + s0 + i) * str + h * 128 + d0 + j);
    __syncthreads();
    short4v r;
#pragma unroll
    for (int p = 0; p < 4; ++p) r[p] = t[j + p][i];
    *(short4v*)(out + ((size_t)bh * 128 + d0 + i) * S + s0 + j) = r;
}

// ---------------------------------------------------------------------------
// Flash attention v8 (verified passing in round 4):
//  - operand-swapped QK^T + in-register P transpose (cvt_pk + permlane)
//  - CAUSAL: tile-pairing (t, NT-1-t) -> balanced 17-chunk blocks
//  - reg-staged K/V prefetch, setprio around PV MFMA cluster
// ---------------------------------------------------------------------------
template <int CAUSAL>
__global__ __launch_bounds__(256) void flash_attn(
    const bf16* __restrict__ Q, int qstr, const bf16* __restrict__ K, int kstr,
    const bf16* __restrict__ Vt, const int* __restrict__ pad,
    bf16* __restrict__ Of, float* __restrict__ Ls, int Sq, int Sk)
{
    __shared__ __align__(16) short Ks[64 * 128];   // 16 KB, swizzled
    __shared__ __align__(16) short Vs[128 * 64];   // 16 KB, swizzled

    const int tid  = threadIdx.x;
    const int lane = tid & 63;
    const int wave = tid >> 6;
    const int quad = lane >> 4;
    const int l16  = lane & 15;
    const int r7   = l16 & 7;
    const int bh   = blockIdx.y;
    const int b    = bh >> 3;
    const int h    = bh & 7;
    const int par  = blockIdx.z;

    const int NT = Sq >> 7;
    const float sc = 0.08838834764831845f * 1.4426950408889634f;  // log2 scale
    const bf16* vb0 = Vt + (size_t)bh * 128 * Sk;
    const short* Kb = (const short*)K + (size_t)b * Sk * kstr + h * 128;

    int krr[4], kgg[4], vrr[4], vgg[4];
#pragma unroll
    for (int s = 0; s < 4; ++s) {
        int seg = wave * 4 + s;
        krr[s] = seg * 4 + (lane >> 4);
        kgg[s] = (l16 ^ (krr[s] & 7)) * 8;
        vrr[s] = seg * 8 + (lane >> 3);
        vgg[s] = ((lane & 7) ^ (vrr[s] & 7)) * 8;
    }

    const int npass = CAUSAL ? 2 : 1;
    for (int ps = 0; ps < npass; ++ps) {
        const int tile = CAUSAL ? (ps ? NT - 1 - (int)blockIdx.x : (int)blockIdx.x)
                                : (int)blockIdx.x;
        const int q0 = tile * 128;
        const int qw = q0 + wave * 32;

        short8 qf[2][4];
#pragma unroll
        for (int mi = 0; mi < 2; ++mi) {
            const bf16* qb = Q + (size_t)(b * Sq + qw + mi * 16 + l16) * qstr + h * 128;
#pragma unroll
            for (int c = 0; c < 4; ++c)
                qf[mi][c] = *(const short8*)(qb + c * 32 + quad * 8);
        }

        floatx4 o[2][8];
#pragma unroll
        for (int mi = 0; mi < 2; ++mi)
#pragma unroll
            for (int nf = 0; nf < 8; ++nf) o[mi][nf] = (floatx4){0.f, 0.f, 0.f, 0.f};
        float lsum[2] = {0.f, 0.f};

        int kEnd = Sk;
        if (CAUSAL && q0 + 128 < Sk) kEnd = q0 + 128;

        intx4 sk[4], sv[4];
        {
            const int kc = par * 64;
#pragma unroll
            for (int s = 0; s < 4; ++s) {
                sk[s] = *(const intx4*)(Kb + (size_t)(kc + krr[s]) * kstr + kgg[s]);
                sv[s] = *(const intx4*)((const short*)vb0 + (size_t)vrr[s] * Sk + kc + vgg[s]);
            }
        }

        for (int ci = par; ci * 64 < kEnd; ci += 2) {
            const int kc = ci * 64;
            __syncthreads();
#pragma unroll
            for (int s = 0; s < 4; ++s) {
                *(intx4*)&Ks[(wave * 4 + s) * 512 + lane * 8] = sk[s];
                *(intx4*)&Vs[(wave * 4 + s) * 512 + lane * 8] = sv[s];
            }
            __syncthreads();

            const int kcn = kc + 128;
            if (kcn < kEnd) {
#pragma unroll
                for (int s = 0; s < 4; ++s) {
                    sk[s] = *(const intx4*)(Kb + (size_t)(kcn + krr[s]) * kstr + kgg[s]);
                    sv[s] = *(const intx4*)((const short*)vb0 + (size_t)vrr[s] * Sk + kcn + vgg[s]);
                }
            }
            __builtin_amdgcn_sched_barrier(0);

            short8 pfm[2][2];
#pragma unroll
            for (int c = 0; c < 2; ++c) {
                floatx4 sT[2][2];
#pragma unroll
                for (int fp = 0; fp < 2; ++fp) {
                    const int f = c * 2 + fp;
                    const int krow = f * 16 + l16;
                    short8 kf[4];
#pragma unroll
                    for (int cc = 0; cc < 4; ++cc)
                        kf[cc] = *(const short8*)&Ks[krow * 128 + (((cc * 4 + quad) ^ r7) << 3)];
#pragma unroll
                    for (int mi = 0; mi < 2; ++mi) {
                        floatx4 s = (floatx4){0.f, 0.f, 0.f, 0.f};
#pragma unroll
                        for (int cc = 0; cc < 4; ++cc)
                            s = __builtin_amdgcn_mfma_f32_16x16x32_bf16(
                                kf[cc], qf[mi][cc], s, 0, 0, 0);
                        sT[mi][fp] = s;
                    }
                }

                const int* pb = pad + (size_t)b * Sk + kc + c * 32 + quad * 4;
                intx4 pv0 = *(const intx4*)pb;
                intx4 pv1 = *(const intx4*)(pb + 16);

#pragma unroll
                for (int mi = 0; mi < 2; ++mi) {
                    const int qv = qw + mi * 16 + l16;
#pragma unroll
                    for (int fp = 0; fp < 2; ++fp) {
#pragma unroll
                        for (int r = 0; r < 4; ++r) {
                            int kk = kc + (c * 2 + fp) * 16 + quad * 4 + r;
                            bool ok = ((fp ? pv1[r] : pv0[r]) != 0);
                            if (CAUSAL) ok = ok && (kk <= qv);
                            float p = ok ? __builtin_amdgcn_exp2f(sT[mi][fp][r] * sc) : 0.f;
                            sT[mi][fp][r] = p;
                            lsum[mi] += p;
                        }
                    }
                    unsigned wA = cvtpk_bf16(sT[mi][0][0], sT[mi][0][1]);
                    unsigned wB = cvtpk_bf16(sT[mi][0][2], sT[mi][0][3]);
                    unsigned wC = cvtpk_bf16(sT[mi][1][0], sT[mi][1][1]);
                    unsigned wD = cvtpk_bf16(sT[mi][1][2], sT[mi][1][3]);
                    pl32swap(wA, wC);
                    pl16swap(wA, wC);
                    pl32swap(wB, wD);
                    pl16swap(wB, wD);
                    uintx4 t;
                    t[0] = wA; t[1] = wB; t[2] = wC; t[3] = wD;
                    pfm[mi][c] = __builtin_bit_cast(short8, t);
                }
            }

            __builtin_amdgcn_s_setprio(1);
#pragma unroll
            for (int nf = 0; nf < 8; ++nf) {
                int vrow = nf * 16 + l16;
                short8 vf0 = *(const short8*)&Vs[vrow * 64 + ((quad ^ r7) << 3)];
                short8 vf1 = *(const short8*)&Vs[vrow * 64 + (((4 + quad) ^ r7) << 3)];
#pragma unroll
                for (int mi = 0; mi < 2; ++mi) {
                    o[mi][nf] = __builtin_amdgcn_mfma_f32_16x16x32_bf16(
                        pfm[mi][0], vf0, o[mi][nf], 0, 0, 0);
                    o[mi][nf] = __builtin_amdgcn_mfma_f32_16x16x32_bf16(
                        pfm[mi][1], vf1, o[mi][nf], 0, 0, 0);
                }
            }
            __builtin_amdgcn_s_setprio(0);
        }

        bf16* op = Of + (size_t)par * B_ * Sq * DM_;
        float* lp = Ls + (size_t)par * B_ * H_ * Sq;
#pragma unroll
        for (int mi = 0; mi < 2; ++mi) {
            float s = lsum[mi];
            s += __shfl_xor(s, 16);
            s += __shfl_xor(s, 32);
            if (lane < 16)
                lp[(size_t)bh * Sq + qw + mi * 16 + l16] = s;
#pragma unroll
            for (int nf = 0; nf < 8; ++nf)
#pragma unroll
                for (int r = 0; r < 4; ++r) {
                    int q = qw + mi * 16 + quad * 4 + r;
                    op[(size_t)(b * Sq + q) * DM_ + h * 128 + nf * 16 + l16] =
                        f2b(o[mi][nf][r]);
                }
        }
    }
}

// combine: out = (O0 + O1) / (L0 + L1)
__global__ __launch_bounds__(256) void attn_combine(
    const bf16* __restrict__ Of, const float* __restrict__ Ls,
    bf16* __restrict__ out)
{
    const int row = blockIdx.x;           // b*SD_+q
    const int t = threadIdx.x;
    const int col = t * 4;
    const int h = col >> 7;
    const int b = row >> 11;
    const int q = row & (SD_ - 1);
    const size_t NV = (size_t)B_ * SD_ * DM_;
    const int idx = (b * H_ + h) * SD_ + q;
    float l = Ls[idx] + Ls[B_ * H_ * SD_ + idx];
    float inv = l > 0.f ? 1.f / l : 0.f;
    size_t base = (size_t)row * DM_ + col;
    short4v a0 = *(const short4v*)(Of + base);
    short4v a1 = *(const short4v*)(Of + NV + base);
    short4v r;
#pragma unroll
    for (int i = 0; i < 4; ++i)
        r[i] = f2s((b2f(__builtin_bit_cast(bf16, (short)a0[i])) +
                    b2f(__builtin_bit_cast(bf16, (short)a1[i]))) * inv);
    *(short4v*)(out + base) = r;
}

// ---------------------------------------------------------------------------
// out = LayerNorm(a + b) * g + beta
// ---------------------------------------------------------------------------
template <int A32, int O32>
__global__ __launch_bounds__(256) void add_ln(
    const void* __restrict__ Ap, const bf16* __restrict__ Bv,
    const float* __restrict__ g, const float* __restrict__ be,
    void* __restrict__ outp)
{
    const int D = DM_;
    __shared__ float red[8];
    const size_t row = blockIdx.x;
    const int t = threadIdx.x;

    float x[4];
    {
        float av[4];
        if (A32) {
            floatx4 a4 = *(const floatx4*)((const float*)Ap + row * D + t * 4);
#pragma unroll
            for (int i = 0; i < 4; ++i) av[i] = a4[i];
        } else {
            short4v a4 = *(const short4v*)((const bf16*)Ap + row * D + t * 4);
#pragma unroll
            for (int i = 0; i < 4; ++i)
                av[i] = b2f(__builtin_bit_cast(bf16, (short)a4[i]));
        }
        short4v b4 = *(const short4v*)(Bv + row * D + t * 4);
#pragma unroll
        for (int i = 0; i < 4; ++i)
            x[i] = av[i] + b2f(__builtin_bit_cast(bf16, (short)b4[i]));
    }
    float s = 0.f, s2 = 0.f;
#pragma unroll
    for (int i = 0; i < 4; ++i) { s += x[i]; s2 += x[i] * x[i]; }
#pragma unroll
    for (int off = 32; off >= 1; off >>= 1) {
        s  += __shfl_xor(s, off);
        s2 += __shfl_xor(s2, off);
    }
    const int wave = t >> 6;
    if ((t & 63) == 0) { red[wave] = s; red[4 + wave] = s2; }
    __syncthreads();
    s  = red[0] + red[1] + red[2] + red[3];
    s2 = red[4] + red[5] + red[6] + red[7];
    const float mu   = s * (1.f / D);
    const float var  = s2 * (1.f / D) - mu * mu;
    const float rstd = rsqrtf(var + 1e-5f);
#pragma unroll
    for (int i = 0; i < 4; ++i) {
        int idx = t * 4 + i;
        float v = (x[i] - mu) * rstd * g[idx] + be[idx];
        if (O32) ((float*)outp)[row * D + idx] = v;
        else     ((bf16*)outp)[row * D + idx] = f2b(v);
    }
}

// ---------------------------------------------------------------------------
extern "C" void kernel_launch(void* const* d_in, const int* in_sizes, int n_in,
                              void* d_out, int out_size, void* d_ws, size_t ws_size,
                              hipStream_t stream)
{
    const float* emb    = (const float*)d_in[0];
    const float* enc    = (const float*)d_in[1];
    const int*  in_pad  = (const int*)d_in[2];
    const int*  out_pad = (const int*)d_in[3];
    const float* q1_w = (const float*)d_in[4];  const float* q1_b = (const float*)d_in[5];
    const float* k1_w = (const float*)d_in[6];  const float* k1_b = (const float*)d_in[7];
    const float* v1_w = (const float*)d_in[8];  const float* v1_b = (const float*)d_in[9];
    const float* q2_w = (const float*)d_in[10]; const float* q2_b = (const float*)d_in[11];
    const float* k2_w = (const float*)d_in[12]; const float* k2_b = (const float*)d_in[13];
    const float* v2_w = (const float*)d_in[14]; const float* v2_b = (const float*)d_in[15];
    const float* sa_qw = (const float*)d_in[16]; const float* sa_qb = (const float*)d_in[17];
    const float* sa_kw = (const float*)d_in[18]; const float* sa_kb = (const float*)d_in[19];
    const float* sa_vw = (const float*)d_in[20]; const float* sa_vb = (const float*)d_in[21];
    const float* sa_ow = (const float*)d_in[22]; const float* sa_ob = (const float*)d_in[23];
    const float* ed_qw = (const float*)d_in[24]; const float* ed_qb = (const float*)d_in[25];
    const float* ed_kw = (const float*)d_in[26]; const float* ed_kb = (const float*)d_in[27];
    const float* ed_vw = (const float*)d_in[28]; const float* ed_vb = (const float*)d_in[29];
    const float* ed_ow = (const float*)d_in[30]; const float* ed_ob = (const float*)d_in[31];
    const float* ff_w1 = (const float*)d_in[32]; const float* ff_b1 = (const float*)d_in[33];
    const float* ff_w2 = (const float*)d_in[34]; const float* ff_b2 = (const float*)d_in[35];
    const float* ln1_g = (const float*)d_in[36]; const float* ln1_b = (const float*)d_in[37];
    const float* ln2_g = (const float*)d_in[38]; const float* ln2_b = (const float*)d_in[39];

    const int M = B_ * SD_;                 // 8192
    const size_t MM = (size_t)1024 * 1024;
    bf16* ws = (bf16*)d_ws;

    // ---- workspace layout (bf16 units) ----
    bf16* Wqkv = ws;                 // [3072,1024]
    bf16* Wkv  = ws + 3 * MM;        // [2048,1024]
    bf16* Wq2  = ws + 5 * MM;
    bf16* Wso  = ws + 6 * MM;
    bf16* Weo  = ws + 7 * MM;
    bf16* Wf1  = ws + 8 * MM;
    bf16* Wf2  = ws + 12 * MM;
    float* bQKV = (float*)(ws + 16 * MM);          // 3072 f
    float* bKV  = bQKV + 3072;                     // 2048 f
    float* bQ2  = bKV + 2048;                      // 1024 f
    float* Lsum = bQ2 + 2048;                      // 2*32*2048 f = 512 KB
    bf16* hw   = ws + 17 * MM;
    bf16* ft   = ws + 23 * MM;
    bf16* emb_b = ws + 17 * MM;      // 8M (aliases hw -- written AFTER gemm_prep)
    bf16* enc_b = ws + 25 * MM;      // 8M (aliases ft tail -- written AFTER gemm_prep)
    bf16* sqkv  = ws + 33 * MM;      // 24M [8192,3072]
    bf16* skv   = ws + 33 * MM;      // 16M [8192,2048] (after flash1)
    bf16* sq2   = ws + 49 * MM;      // 8M
    bf16* sVt   = ws + 57 * MM;      // 8M  [32][128][2048]
    bf16* attn  = ws + 65 * MM;      // 8M
    bf16* Ofb   = ws + 73 * MM;      // 16M (2 splits x 8M, unnormalized O)
    bf16* s1    = ws + 73 * MM;      // 8M (reused after combine)
    bf16* x     = ws + 89 * MM;      // 8M
    bf16* y     = ws + 33 * MM;      // 8M (after flash2)
    bf16* mid   = ws + 41 * MM;      // 32M
    bf16* f2    = ws + 81 * MM;      // 8M

    auto G = [&](const bf16* Ai, const bf16* Wi, const float* bi, bf16* Ci,
                 int Mi, int Ni, int Ki, bool relu) {
        dim3 grid(Ni / 128, Mi / 256);
        if (relu) gemm256<1><<<grid, 512, 0, stream>>>(Ai, Wi, bi, Ci, Mi, Ni, Ki);
        else      gemm256<0><<<grid, 512, 0, stream>>>(Ai, Wi, bi, Ci, Mi, Ni, Ki);
    };

    // ---- weight preparation (batched; ORDER MATTERS: gemm_prep must consume
    //      hw/ft BEFORE the misc convert overwrites them via emb_b/enc_b) ----
    {   // 6 per-head weight converts -> hw
        PtrsIn in; PtrsOut out; Int6 n;
        const float* s6[6] = {sa_qw, sa_kw, sa_vw, ed_qw, ed_kw, ed_vw};
        for (int i = 0; i < 6; ++i) { in.p[i] = s6[i]; out.p[i] = hw + i * MM; n.v[i] = (int)MM; }
        cvt6<<<dim3(512, 6), 256, 0, stream>>>(in, out, n);
    }
    {   // 6 transposed linear-weight converts -> ft
        PtrsIn in;
        const float* s6[6] = {q1_w, k1_w, v1_w, q2_w, k2_w, v2_w};
        for (int i = 0; i < 6; ++i) in.p[i] = s6[i];
        cvtT6<<<dim3(32, 32, 6), 256, 0, stream>>>(in, ft);
    }
    {   // 6 weight-compose GEMMs (one launch, 384 blocks) -- reads hw+ft
        PtrsIn A, W; PtrsOut C;
        const int idx[6] = {0, 1, 2, 4, 5, 3};
        bf16* c6[6] = {Wqkv, Wqkv + MM, Wqkv + 2 * MM, Wkv, Wkv + MM, Wq2};
        for (int i = 0; i < 6; ++i) {
            A.p[i] = hw + (size_t)idx[i] * MM;
            W.p[i] = ft + (size_t)idx[i] * MM;
            C.p[i] = c6[i];
        }
        gemm_prep<<<dim3(8, 8, 6), 256, 0, stream>>>(A, W, C);
    }
    {   // 6 composed biases (reads original f32 inputs only)
        PtrsIn w, bi, ba; PtrsOut o;
        const float* w6[6]  = {sa_qw, sa_kw, sa_vw, ed_kw, ed_vw, ed_qw};
        const float* bi6[6] = {q1_b, k1_b, v1_b, k2_b, v2_b, q2_b};
        const float* ba6[6] = {sa_qb, sa_kb, sa_vb, ed_kb, ed_vb, ed_qb};
        float* o6[6] = {bQKV, bQKV + 1024, bQKV + 2048, bKV, bKV + 1024, bQ2};
        for (int i = 0; i < 6; ++i) { w.p[i] = w6[i]; bi.p[i] = bi6[i]; ba.p[i] = ba6[i]; o.p[i] = o6[i]; }
        bias6<<<dim3(1024, 6), 256, 0, stream>>>(w, bi, ba, o);
    }
    {   // misc converts: proj/FFN weights + activations (overwrites hw/ft region)
        PtrsIn in; PtrsOut out; Int6 n;
        const float* s6[6] = {sa_ow, ed_ow, ff_w1, ff_w2, emb, enc};
        void* d6[6] = {Wso, Weo, Wf1, Wf2, emb_b, enc_b};
        int n6[6] = {(int)MM, (int)MM, (int)(4 * MM), (int)(4 * MM), (int)(8 * MM), (int)(8 * MM)};
        for (int i = 0; i < 6; ++i) { in.p[i] = s6[i]; out.p[i] = d6[i]; n.v[i] = n6[i]; }
        cvt6<<<dim3(4096, 6), 256, 0, stream>>>(in, out, n);
    }

    // ---- self attention ----
    G(emb_b, Wqkv, bQKV, sqkv, M, 3072, DM_, false);          // Qh|Kh|Vh
    vtrans<<<dim3(SD_ / 32, 4, B_ * H_), 256, 0, stream>>>(sqkv + 2048, 3072, sVt, SD_);
    flash_attn<1><<<dim3(SD_ / 256, B_ * H_, 2), 256, 0, stream>>>(
        sqkv, 3072, sqkv + 1024, 3072, sVt, out_pad, Ofb, Lsum, SD_, SD_);
    attn_combine<<<dim3(M), 256, 0, stream>>>(Ofb, Lsum, attn);
    G(attn, Wso, sa_ob, s1, M, DM_, DM_, false);
    add_ln<1, 0><<<dim3(M), 256, 0, stream>>>(emb, s1, ln1_g, ln1_b, x);

    // ---- cross attention (residual from emb, per reference) ----
    G(enc_b, Wkv, bKV, skv, M, 2048, DM_, false);             // Kh2|Vh2
    G(x, Wq2, bQ2, sq2, M, DM_, DM_, false);                  // Qh2
    vtrans<<<dim3(SE_ / 32, 4, B_ * H_), 256, 0, stream>>>(skv + 1024, 2048, sVt, SE_);
    flash_attn<0><<<dim3(SD_ / 128, B_ * H_, 2), 256, 0, stream>>>(
        sq2, 1024, skv, 2048, sVt, in_pad, Ofb, Lsum, SD_, SE_);
    attn_combine<<<dim3(M), 256, 0, stream>>>(Ofb, Lsum, attn);
    G(attn, Weo, ed_ob, s1, M, DM_, DM_, false);
    add_ln<1, 0><<<dim3(M), 256, 0, stream>>>(emb, s1, ln2_g, ln2_b, y);

    // ---- FFN (final norm reuses ln2 params, per reference) ----
    G(y, Wf1, ff_b1, mid, M, DFF_, DM_, true);
    G(mid, Wf2, ff_b2, f2, M, DM_, DFF_, false);
    add_ln<0, 1><<<dim3(M), 256, 0, stream>>>(y, f2, ln2_g, ln2_b, d_out);
}

// Round 8
// 830.173 us; speedup vs baseline: 1.3193x; 1.0357x over previous
//
#include <hip/hip_runtime.h>
#include <hip/hip_bf16.h>

typedef __hip_bfloat16 bf16;
typedef short short8 __attribute__((ext_vector_type(8)));
typedef short short4v __attribute__((ext_vector_type(4)));
typedef float floatx4 __attribute__((ext_vector_type(4)));
typedef int intx4 __attribute__((ext_vector_type(4)));
typedef unsigned int uintx4 __attribute__((ext_vector_type(4)));

#define B_ 4
#define SD_ 2048
#define SE_ 2048
#define DM_ 1024
#define H_ 8
#define DFF_ 4096

struct PtrsIn  { const void* p[6]; };
struct PtrsOut { void* p[6]; };
struct Int6    { int v[6]; };

__device__ __forceinline__ float b2f(bf16 v) { return __bfloat162float(v); }
__device__ __forceinline__ bf16 f2b(float v) { return __float2bfloat16(v); }
__device__ __forceinline__ short f2s(float v) { return __builtin_bit_cast(short, __float2bfloat16(v)); }

// pack two f32 -> one u32 of 2x bf16 (lo = first arg)
__device__ __forceinline__ unsigned cvtpk_bf16(float lo, float hi) {
    unsigned r;
    asm("v_cvt_pk_bf16_f32 %0, %1, %2" : "=v"(r) : "v"(lo), "v"(hi));
    return r;
}
__device__ __forceinline__ void pl32swap(unsigned &x, unsigned &y) {
    asm("v_permlane32_swap_b32 %0, %1" : "+v"(x), "+v"(y));
}
__device__ __forceinline__ void pl16swap(unsigned &x, unsigned &y) {
    asm("v_permlane16_swap_b32 %0, %1" : "+v"(x), "+v"(y));
}

// async global->LDS, 16B/lane. LDS dest = wave-uniform base + lane*16.
__device__ __forceinline__ void gl_lds16(const short* g, short* l) {
    __builtin_amdgcn_global_load_lds(
        (const __attribute__((address_space(1))) void*)g,
        (__attribute__((address_space(3))) void*)l, 16, 0, 0);
}

// ---------------------------------------------------------------------------
// batched f32->bf16 convert: segment y, per-segment element count n.v[y]
// ---------------------------------------------------------------------------
__global__ __launch_bounds__(256) void cvt6(PtrsIn in, PtrsOut out, Int6 n)
{
    const int y = blockIdx.y;
    int i = (blockIdx.x * 256 + threadIdx.x) * 8;
    if (i >= n.v[y]) return;
    const float* src = (const float*)in.p[y];
    bf16* dst = (bf16*)out.p[y];
    floatx4 a = *(const floatx4*)(src + i);
    floatx4 b = *(const floatx4*)(src + i + 4);
    short8 r;
#pragma unroll
    for (int k = 0; k < 4; ++k) { r[k] = f2s(a[k]); r[k + 4] = f2s(b[k]); }
    *(short8*)(dst + i) = r;
}

// batched fp32 [1024,1024] -> bf16 transposed (segment z -> out + z*1M)
__global__ __launch_bounds__(256) void cvtT6(PtrsIn in, bf16* out)
{
    __shared__ short tl[32][36];
    const int z = blockIdx.z;
    const float* src = (const float*)in.p[z];
    bf16* dst = out + (size_t)z * 1024 * 1024;
    const int tid = threadIdx.x;
    const int i = tid >> 3;
    const int j = (tid & 7) * 4;
    const int r0 = blockIdx.x * 32, c0 = blockIdx.y * 32;
    floatx4 v = *(const floatx4*)(src + (size_t)(r0 + i) * 1024 + c0 + j);
#pragma unroll
    for (int p = 0; p < 4; ++p) tl[i][j + p] = f2s(v[p]);
    __syncthreads();
    short4v r;
#pragma unroll
    for (int p = 0; p < 4; ++p) r[p] = tl[j + p][i];
    *(short4v*)(dst + (size_t)(c0 + i) * 1024 + r0 + j) = r;
}

// batched composed bias: segment y: out[o] = sum_m w[o,m]*bin[m] + badd[o]
__global__ __launch_bounds__(256) void bias6(
    PtrsIn w6, PtrsIn bin6, PtrsIn badd6, PtrsOut out6)
{
    __shared__ float red[4];
    const int y = blockIdx.y;
    const float* w    = (const float*)w6.p[y];
    const float* bin  = (const float*)bin6.p[y];
    const float* badd = (const float*)badd6.p[y];
    float* out        = (float*)out6.p[y];
    const int o = blockIdx.x;
    const int t = threadIdx.x;
    float s = 0.f;
#pragma unroll
    for (int i = t; i < 1024; i += 256) s += w[(size_t)o * 1024 + i] * bin[i];
#pragma unroll
    for (int off = 32; off >= 1; off >>= 1) s += __shfl_xor(s, off);
    if ((t & 63) == 0) red[t >> 6] = s;
    __syncthreads();
    if (t == 0) out[o] = red[0] + red[1] + red[2] + red[3] + badd[o];
}

// ---------------------------------------------------------------------------
// gemm_prep: batched 1024^3 weight-compose GEMMs (z selects problem).
// 128x128 tile, gl_lds staging with XOR swizzle (legacy gemm_bt body).
// ---------------------------------------------------------------------------
__global__ __launch_bounds__(256) void gemm_prep(PtrsIn A6, PtrsIn W6, PtrsOut C6)
{
    __shared__ __align__(16) short As[16 * 512];
    __shared__ __align__(16) short Ws[16 * 512];

    const int K = 1024, N = 1024;
    const int z = blockIdx.z;
    const bf16* A = (const bf16*)A6.p[z];
    const bf16* W = (const bf16*)W6.p[z];
    bf16* C = (bf16*)C6.p[z];

    const int tid  = threadIdx.x;
    const int lane = tid & 63;
    const int wave = tid >> 6;
    const int quad = lane >> 4;
    const int l16  = lane & 15;
    const int r7   = l16 & 7;
    const int bm0  = blockIdx.y * 128;
    const int bn0  = blockIdx.x * 128;
    const int wm   = (wave >> 1) * 64;
    const int wn   = (wave & 1) * 64;

    const int scol = (((lane & 7) ^ (lane >> 3)) * 8);
    const short* Ag = (const short*)A + (size_t)(bm0 + wave * 32 + (lane >> 3)) * K + scol;
    const short* Wg = (const short*)W + (size_t)(bn0 + wave * 32 + (lane >> 3)) * K + scol;
    short* Al = As + (wave * 4) * 512;
    short* Wl = Ws + (wave * 4) * 512;

    floatx4 acc[4][4];
#pragma unroll
    for (int i = 0; i < 4; ++i)
#pragma unroll
        for (int j = 0; j < 4; ++j)
            acc[i][j] = (floatx4){0.f, 0.f, 0.f, 0.f};

    for (int k0 = 0; k0 < K; k0 += 64) {
        __syncthreads();
#pragma unroll
        for (int s = 0; s < 4; ++s) {
            gl_lds16(Ag + k0 + (size_t)s * 8 * K, Al + s * 512);
            gl_lds16(Wg + k0 + (size_t)s * 8 * K, Wl + s * 512);
        }
        __syncthreads();
#pragma unroll
        for (int kk = 0; kk < 64; kk += 32) {
            short8 af[4], bg[4];
#pragma unroll
            for (int i = 0; i < 4; ++i) {
                int row = wm + i * 16 + l16;
                af[i] = *(const short8*)&As[(row >> 3) * 512 + r7 * 64 +
                                            (((quad + (kk >> 3)) ^ r7) << 3)];
            }
#pragma unroll
            for (int j = 0; j < 4; ++j) {
                int row = wn + j * 16 + l16;
                bg[j] = *(const short8*)&Ws[(row >> 3) * 512 + r7 * 64 +
                                            (((quad + (kk >> 3)) ^ r7) << 3)];
            }
#pragma unroll
            for (int i = 0; i < 4; ++i)
#pragma unroll
                for (int j = 0; j < 4; ++j)
                    acc[i][j] = __builtin_amdgcn_mfma_f32_16x16x32_bf16(
                        af[i], bg[j], acc[i][j], 0, 0, 0);
        }
    }

#pragma unroll
    for (int j = 0; j < 4; ++j) {
        int col = bn0 + wn + j * 16 + l16;
#pragma unroll
        for (int i = 0; i < 4; ++i) {
            int row0 = bm0 + wm + i * 16 + quad * 4;
#pragma unroll
            for (int r = 0; r < 4; ++r)
                C[(size_t)(row0 + r) * N + col] = f2b(acc[i][j][r]);
        }
    }
}

// ---------------------------------------------------------------------------
// gemm256: C = act(A @ W^T + bias), BM=256 x BN=128 x BK=64, 8 waves.
// Triple-buffered LDS, counted vmcnt(6), XOR swizzle, XCD swizzle, setprio.
// ---------------------------------------------------------------------------
template <int RELU>
__global__ __launch_bounds__(512, 2) void gemm256(
    const bf16* __restrict__ A, const bf16* __restrict__ W,
    const float* __restrict__ bias, bf16* __restrict__ C,
    int M, int N, int K)
{
    __shared__ __align__(16) short L[3 * 24576];   // 3 x (A 256x64 + B 128x64)

    const int tid  = threadIdx.x;
    const int lane = tid & 63;
    const int wave = tid >> 6;       // 0..7
    const int quad = lane >> 4;
    const int l16  = lane & 15;
    const int r7   = l16 & 7;
    const int wm   = wave >> 1;      // 0..3  (m-quarter)
    const int wn   = wave & 1;       // 0..1  (n-half)

    const int gx  = gridDim.x;
    const int nwg = gx * gridDim.y;
    int wg = blockIdx.y * gx + blockIdx.x;
    if ((nwg & 7) == 0) wg = (wg & 7) * (nwg >> 3) + (wg >> 3);
    const int bn0 = (wg % gx) * 128;
    const int bm0 = (wg / gx) * 256;

    const int scol = (((lane & 7) ^ ((lane >> 3) & 7)) * 8);
    const short* Ag = (const short*)A + (size_t)(bm0 + wave * 32 + (lane >> 3)) * K + scol;
    const short* Wg = (const short*)W + (size_t)(bn0 + wave * 16 + (lane >> 3)) * K + scol;
    const int aw = (wave * 32) * 64;
    const int bw = 16384 + (wave * 16) * 64;

    floatx4 acc[4][4];
#pragma unroll
    for (int i = 0; i < 4; ++i)
#pragma unroll
        for (int j = 0; j < 4; ++j)
            acc[i][j] = (floatx4){0.f, 0.f, 0.f, 0.f};

    const int T = K / 64;

#pragma unroll
    for (int i = 0; i < 4; ++i) gl_lds16(Ag + (size_t)(i * 8) * K, L + aw + i * 8 * 64);
#pragma unroll
    for (int i = 0; i < 2; ++i) gl_lds16(Wg + (size_t)(i * 8) * K, L + bw + i * 8 * 64);
#pragma unroll
    for (int i = 0; i < 4; ++i) gl_lds16(Ag + 64 + (size_t)(i * 8) * K, L + 24576 + aw + i * 8 * 64);
#pragma unroll
    for (int i = 0; i < 2; ++i) gl_lds16(Wg + 64 + (size_t)(i * 8) * K, L + 24576 + bw + i * 8 * 64);
    asm volatile("s_waitcnt vmcnt(6)" ::: "memory");
    __builtin_amdgcn_s_barrier();

    int cur = 0, stg = 2;
    for (int t = 0; t < T; ++t) {
        __builtin_amdgcn_sched_barrier(0);
        const int kt = (t + 2 < T) ? (t + 2) : (T - 1);
        const size_t kg = (size_t)kt * 64;
        const short* Ac = L + cur * 24576;
        const short* Bc = Ac + 16384;
        short* As_s = L + stg * 24576 + aw;
        short* Bs_s = L + stg * 24576 + bw;

        short8 af[2][2], bf[4][2];

        // phase 0: m-frags 0,1
#pragma unroll
        for (int mi = 0; mi < 2; ++mi)
#pragma unroll
            for (int ks = 0; ks < 2; ++ks)
                af[mi][ks] = *(const short8*)&Ac[(wm * 64 + mi * 16 + l16) * 64 +
                                                (((ks * 4 + quad) ^ r7) << 3)];
#pragma unroll
        for (int nf = 0; nf < 4; ++nf)
#pragma unroll
            for (int ks = 0; ks < 2; ++ks)
                bf[nf][ks] = *(const short8*)&Bc[(wn * 64 + nf * 16 + l16) * 64 +
                                                (((ks * 4 + quad) ^ r7) << 3)];
        gl_lds16(Ag + kg, As_s);
        gl_lds16(Ag + kg + (size_t)8 * K, As_s + 8 * 64);
        gl_lds16(Wg + kg, Bs_s);
        __builtin_amdgcn_s_barrier();
        asm volatile("s_waitcnt lgkmcnt(0)" ::: "memory");
        __builtin_amdgcn_sched_barrier(0);
        __builtin_amdgcn_s_setprio(1);
#pragma unroll
        for (int ks = 0; ks < 2; ++ks)
#pragma unroll
            for (int mi = 0; mi < 2; ++mi)
#pragma unroll
                for (int nf = 0; nf < 4; ++nf)
                    acc[mi][nf] = __builtin_amdgcn_mfma_f32_16x16x32_bf16(
                        af[mi][ks], bf[nf][ks], acc[mi][nf], 0, 0, 0);
        __builtin_amdgcn_s_setprio(0);
        __builtin_amdgcn_s_barrier();

        // phase 1: m-frags 2,3
#pragma unroll
        for (int mi = 0; mi < 2; ++mi)
#pragma unroll
            for (int ks = 0; ks < 2; ++ks)
                af[mi][ks] = *(const short8*)&Ac[(wm * 64 + (2 + mi) * 16 + l16) * 64 +
                                                (((ks * 4 + quad) ^ r7) << 3)];
        gl_lds16(Ag + kg + (size_t)16 * K, As_s + 16 * 64);
        gl_lds16(Ag + kg + (size_t)24 * K, As_s + 24 * 64);
        gl_lds16(Wg + kg + (size_t)8 * K, Bs_s + 8 * 64);
        __builtin_amdgcn_s_barrier();
        asm volatile("s_waitcnt lgkmcnt(0)" ::: "memory");
        __builtin_amdgcn_sched_barrier(0);
        __builtin_amdgcn_s_setprio(1);
#pragma unroll
        for (int ks = 0; ks < 2; ++ks)
#pragma unroll
            for (int mi = 0; mi < 2; ++mi)
#pragma unroll
                for (int nf = 0; nf < 4; ++nf)
                    acc[2 + mi][nf] = __builtin_amdgcn_mfma_f32_16x16x32_bf16(
                        af[mi][ks], bf[nf][ks], acc[2 + mi][nf], 0, 0, 0);
        __builtin_amdgcn_s_setprio(0);
        asm volatile("s_waitcnt vmcnt(6)" ::: "memory");
        __builtin_amdgcn_s_barrier();

        cur = (cur == 2) ? 0 : cur + 1;
        stg = (stg == 2) ? 0 : stg + 1;
    }

#pragma unroll
    for (int nf = 0; nf < 4; ++nf) {
        int col = bn0 + wn * 64 + nf * 16 + l16;
        float bv = bias ? bias[col] : 0.f;
#pragma unroll
        for (int mf = 0; mf < 4; ++mf) {
            int row0 = bm0 + wm * 64 + mf * 16 + quad * 4;
#pragma unroll
            for (int r = 0; r < 4; ++r) {
                float v = acc[mf][nf][r] + bv;
                if (RELU) v = fmaxf(v, 0.f);
                C[(size_t)(row0 + r) * N + col] = f2b(v);
            }
        }
    }
}

// ---------------------------------------------------------------------------
// V transpose: in rows [B*S, str] (head h at col h*128) -> out [B*H][128][S]
// ---------------------------------------------------------------------------
__global__ __launch_bounds__(256) void vtrans(
    const bf16* __restrict__ in, int str, bf16* __restrict__ out, int S)
{
    __shared__ short t[32][36];
    const int tid = threadIdx.x;
    const int s0  = blockIdx.x * 32;
    const int d0  = blockIdx.y * 32;
    const int bh  = blockIdx.z;
    const int b = bh >> 3, h = bh & 7;
    const int i = tid >> 3;
    const int j = (tid & 7) * 4;

    *(short4v*)&t[i][j] =
        *(const short4v*)(in + (size_t)(b * S + s0 + i) * str + h * 128 + d0 + j);
    __syncthreads();
    short4v r;
#pragma unroll
    for (int p = 0; p < 4; ++p) r[p] = t[j + p][i];
    *(short4v*)(out + ((size_t)bh * 128 + d0 + i) * S + s0 + j) = r;
}

// ---------------------------------------------------------------------------
// Flash attention v9:
//  - grid reordered to (bh, par, tile) so consecutive linear block ids are
//    consecutive bh -> each XCD sees only bh = xcd (mod 8): K/V working set
//    per XCD = 4 bh x 1 MB = 4 MB = L2 capacity (K/V become L2-resident).
//  - otherwise identical to v8: operand-swapped QK^T, in-register P
//    transpose, causal tile-pairing, reg-staged K/V prefetch, setprio.
// ---------------------------------------------------------------------------
template <int CAUSAL>
__global__ __launch_bounds__(256) void flash_attn(
    const bf16* __restrict__ Q, int qstr, const bf16* __restrict__ K, int kstr,
    const bf16* __restrict__ Vt, const int* __restrict__ pad,
    bf16* __restrict__ Of, float* __restrict__ Ls, int Sq, int Sk)
{
    __shared__ __align__(16) short Ks[64 * 128];   // 16 KB, swizzled
    __shared__ __align__(16) short Vs[128 * 64];   // 16 KB, swizzled

    const int tid  = threadIdx.x;
    const int lane = tid & 63;
    const int wave = tid >> 6;
    const int quad = lane >> 4;
    const int l16  = lane & 15;
    const int r7   = l16 & 7;
    const int bh   = blockIdx.x;          // bh fastest -> XCD-local K/V
    const int b    = bh >> 3;
    const int h    = bh & 7;
    const int par  = blockIdx.y;
    const int tz   = blockIdx.z;

    const int NT = Sq >> 7;
    const float sc = 0.08838834764831845f * 1.4426950408889634f;  // log2 scale
    const bf16* vb0 = Vt + (size_t)bh * 128 * Sk;
    const short* Kb = (const short*)K + (size_t)b * Sk * kstr + h * 128;

    int krr[4], kgg[4], vrr[4], vgg[4];
#pragma unroll
    for (int s = 0; s < 4; ++s) {
        int seg = wave * 4 + s;
        krr[s] = seg * 4 + (lane >> 4);
        kgg[s] = (l16 ^ (krr[s] & 7)) * 8;
        vrr[s] = seg * 8 + (lane >> 3);
        vgg[s] = ((lane & 7) ^ (vrr[s] & 7)) * 8;
    }

    const int npass = CAUSAL ? 2 : 1;
    for (int ps = 0; ps < npass; ++ps) {
        const int tile = CAUSAL ? (ps ? NT - 1 - tz : tz) : tz;
        const int q0 = tile * 128;
        const int qw = q0 + wave * 32;

        short8 qf[2][4];
#pragma unroll
        for (int mi = 0; mi < 2; ++mi) {
            const bf16* qb = Q + (size_t)(b * Sq + qw + mi * 16 + l16) * qstr + h * 128;
#pragma unroll
            for (int c = 0; c < 4; ++c)
                qf[mi][c] = *(const short8*)(qb + c * 32 + quad * 8);
        }

        floatx4 o[2][8];
#pragma unroll
        for (int mi = 0; mi < 2; ++mi)
#pragma unroll
            for (int nf = 0; nf < 8; ++nf) o[mi][nf] = (floatx4){0.f, 0.f, 0.f, 0.f};
        float lsum[2] = {0.f, 0.f};

        int kEnd = Sk;
        if (CAUSAL && q0 + 128 < Sk) kEnd = q0 + 128;

        intx4 sk[4], sv[4];
        {
            const int kc = par * 64;
#pragma unroll
            for (int s = 0; s < 4; ++s) {
                sk[s] = *(const intx4*)(Kb + (size_t)(kc + krr[s]) * kstr + kgg[s]);
                sv[s] = *(const intx4*)((const short*)vb0 + (size_t)vrr[s] * Sk + kc + vgg[s]);
            }
        }

        for (int ci = par; ci * 64 < kEnd; ci += 2) {
            const int kc = ci * 64;
            __syncthreads();
#pragma unroll
            for (int s = 0; s < 4; ++s) {
                *(intx4*)&Ks[(wave * 4 + s) * 512 + lane * 8] = sk[s];
                *(intx4*)&Vs[(wave * 4 + s) * 512 + lane * 8] = sv[s];
            }
            __syncthreads();

            const int kcn = kc + 128;
            if (kcn < kEnd) {
#pragma unroll
                for (int s = 0; s < 4; ++s) {
                    sk[s] = *(const intx4*)(Kb + (size_t)(kcn + krr[s]) * kstr + kgg[s]);
                    sv[s] = *(const intx4*)((const short*)vb0 + (size_t)vrr[s] * Sk + kcn + vgg[s]);
                }
            }
            __builtin_amdgcn_sched_barrier(0);

            short8 pfm[2][2];
#pragma unroll
            for (int c = 0; c < 2; ++c) {
                floatx4 sT[2][2];
#pragma unroll
                for (int fp = 0; fp < 2; ++fp) {
                    const int f = c * 2 + fp;
                    const int krow = f * 16 + l16;
                    short8 kf[4];
#pragma unroll
                    for (int cc = 0; cc < 4; ++cc)
                        kf[cc] = *(const short8*)&Ks[krow * 128 + (((cc * 4 + quad) ^ r7) << 3)];
#pragma unroll
                    for (int mi = 0; mi < 2; ++mi) {
                        floatx4 s = (floatx4){0.f, 0.f, 0.f, 0.f};
#pragma unroll
                        for (int cc = 0; cc < 4; ++cc)
                            s = __builtin_amdgcn_mfma_f32_16x16x32_bf16(
                                kf[cc], qf[mi][cc], s, 0, 0, 0);
                        sT[mi][fp] = s;
                    }
                }

                const int* pb = pad + (size_t)b * Sk + kc + c * 32 + quad * 4;
                intx4 pv0 = *(const intx4*)pb;
                intx4 pv1 = *(const intx4*)(pb + 16);

#pragma unroll
                for (int mi = 0; mi < 2; ++mi) {
                    const int qv = qw + mi * 16 + l16;
#pragma unroll
                    for (int fp = 0; fp < 2; ++fp) {
#pragma unroll
                        for (int r = 0; r < 4; ++r) {
                            int kk = kc + (c * 2 + fp) * 16 + quad * 4 + r;
                            bool ok = ((fp ? pv1[r] : pv0[r]) != 0);
                            if (CAUSAL) ok = ok && (kk <= qv);
                            float p = ok ? __builtin_amdgcn_exp2f(sT[mi][fp][r] * sc) : 0.f;
                            sT[mi][fp][r] = p;
                            lsum[mi] += p;
                        }
                    }
                    unsigned wA = cvtpk_bf16(sT[mi][0][0], sT[mi][0][1]);
                    unsigned wB = cvtpk_bf16(sT[mi][0][2], sT[mi][0][3]);
                    unsigned wC = cvtpk_bf16(sT[mi][1][0], sT[mi][1][1]);
                    unsigned wD = cvtpk_bf16(sT[mi][1][2], sT[mi][1][3]);
                    pl32swap(wA, wC);
                    pl16swap(wA, wC);
                    pl32swap(wB, wD);
                    pl16swap(wB, wD);
                    uintx4 t;
                    t[0] = wA; t[1] = wB; t[2] = wC; t[3] = wD;
                    pfm[mi][c] = __builtin_bit_cast(short8, t);
                }
            }

            __builtin_amdgcn_s_setprio(1);
#pragma unroll
            for (int nf = 0; nf < 8; ++nf) {
                int vrow = nf * 16 + l16;
                short8 vf0 = *(const short8*)&Vs[vrow * 64 + ((quad ^ r7) << 3)];
                short8 vf1 = *(const short8*)&Vs[vrow * 64 + (((4 + quad) ^ r7) << 3)];
#pragma unroll
                for (int mi = 0; mi < 2; ++mi) {
                    o[mi][nf] = __builtin_amdgcn_mfma_f32_16x16x32_bf16(
                        pfm[mi][0], vf0, o[mi][nf], 0, 0, 0);
                    o[mi][nf] = __builtin_amdgcn_mfma_f32_16x16x32_bf16(
                        pfm[mi][1], vf1, o[mi][nf], 0, 0, 0);
                }
            }
            __builtin_amdgcn_s_setprio(0);
        }

        bf16* op = Of + (size_t)par * B_ * Sq * DM_;
        float* lp = Ls + (size_t)par * B_ * H_ * Sq;
#pragma unroll
        for (int mi = 0; mi < 2; ++mi) {
            float s = lsum[mi];
            s += __shfl_xor(s, 16);
            s += __shfl_xor(s, 32);
            if (lane < 16)
                lp[(size_t)bh * Sq + qw + mi * 16 + l16] = s;
#pragma unroll
            for (int nf = 0; nf < 8; ++nf)
#pragma unroll
                for (int r = 0; r < 4; ++r) {
                    int q = qw + mi * 16 + quad * 4 + r;
                    op[(size_t)(b * Sq + q) * DM_ + h * 128 + nf * 16 + l16] =
                        f2b(o[mi][nf][r]);
                }
        }
    }
}

// combine: out = (O0 + O1) / (L0 + L1)
__global__ __launch_bounds__(256) void attn_combine(
    const bf16* __restrict__ Of, const float* __restrict__ Ls,
    bf16* __restrict__ out)
{
    const int row = blockIdx.x;           // b*SD_+q
    const int t = threadIdx.x;
    const int col = t * 4;
    const int h = col >> 7;
    const int b = row >> 11;
    const int q = row & (SD_ - 1);
    const size_t NV = (size_t)B_ * SD_ * DM_;
    const int idx = (b * H_ + h) * SD_ + q;
    float l = Ls[idx] + Ls[B_ * H_ * SD_ + idx];
    float inv = l > 0.f ? 1.f / l : 0.f;
    size_t base = (size_t)row * DM_ + col;
    short4v a0 = *(const short4v*)(Of + base);
    short4v a1 = *(const short4v*)(Of + NV + base);
    short4v r;
#pragma unroll
    for (int i = 0; i < 4; ++i)
        r[i] = f2s((b2f(__builtin_bit_cast(bf16, (short)a0[i])) +
                    b2f(__builtin_bit_cast(bf16, (short)a1[i]))) * inv);
    *(short4v*)(out + base) = r;
}

// ---------------------------------------------------------------------------
// out = LayerNorm(a + b) * g + beta
// ---------------------------------------------------------------------------
template <int A32, int O32>
__global__ __launch_bounds__(256) void add_ln(
    const void* __restrict__ Ap, const bf16* __restrict__ Bv,
    const float* __restrict__ g, const float* __restrict__ be,
    void* __restrict__ outp)
{
    const int D = DM_;
    __shared__ float red[8];
    const size_t row = blockIdx.x;
    const int t = threadIdx.x;

    float x[4];
    {
        float av[4];
        if (A32) {
            floatx4 a4 = *(const floatx4*)((const float*)Ap + row * D + t * 4);
#pragma unroll
            for (int i = 0; i < 4; ++i) av[i] = a4[i];
        } else {
            short4v a4 = *(const short4v*)((const bf16*)Ap + row * D + t * 4);
#pragma unroll
            for (int i = 0; i < 4; ++i)
                av[i] = b2f(__builtin_bit_cast(bf16, (short)a4[i]));
        }
        short4v b4 = *(const short4v*)(Bv + row * D + t * 4);
#pragma unroll
        for (int i = 0; i < 4; ++i)
            x[i] = av[i] + b2f(__builtin_bit_cast(bf16, (short)b4[i]));
    }
    float s = 0.f, s2 = 0.f;
#pragma unroll
    for (int i = 0; i < 4; ++i) { s += x[i]; s2 += x[i] * x[i]; }
#pragma unroll
    for (int off = 32; off >= 1; off >>= 1) {
        s  += __shfl_xor(s, off);
        s2 += __shfl_xor(s2, off);
    }
    const int wave = t >> 6;
    if ((t & 63) == 0) { red[wave] = s; red[4 + wave] = s2; }
    __syncthreads();
    s  = red[0] + red[1] + red[2] + red[3];
    s2 = red[4] + red[5] + red[6] + red[7];
    const float mu   = s * (1.f / D);
    const float var  = s2 * (1.f / D) - mu * mu;
    const float rstd = rsqrtf(var + 1e-5f);
#pragma unroll
    for (int i = 0; i < 4; ++i) {
        int idx = t * 4 + i;
        float v = (x[i] - mu) * rstd * g[idx] + be[idx];
        if (O32) ((float*)outp)[row * D + idx] = v;
        else     ((bf16*)outp)[row * D + idx] = f2b(v);
    }
}

// ---------------------------------------------------------------------------
extern "C" void kernel_launch(void* const* d_in, const int* in_sizes, int n_in,
                              void* d_out, int out_size, void* d_ws, size_t ws_size,
                              hipStream_t stream)
{
    const float* emb    = (const float*)d_in[0];
    const float* enc    = (const float*)d_in[1];
    const int*  in_pad  = (const int*)d_in[2];
    const int*  out_pad = (const int*)d_in[3];
    const float* q1_w = (const float*)d_in[4];  const float* q1_b = (const float*)d_in[5];
    const float* k1_w = (const float*)d_in[6];  const float* k1_b = (const float*)d_in[7];
    const float* v1_w = (const float*)d_in[8];  const float* v1_b = (const float*)d_in[9];
    const float* q2_w = (const float*)d_in[10]; const float* q2_b = (const float*)d_in[11];
    const float* k2_w = (const float*)d_in[12]; const float* k2_b = (const float*)d_in[13];
    const float* v2_w = (const float*)d_in[14]; const float* v2_b = (const float*)d_in[15];
    const float* sa_qw = (const float*)d_in[16]; const float* sa_qb = (const float*)d_in[17];
    const float* sa_kw = (const float*)d_in[18]; const float* sa_kb = (const float*)d_in[19];
    const float* sa_vw = (const float*)d_in[20]; const float* sa_vb = (const float*)d_in[21];
    const float* sa_ow = (const float*)d_in[22]; const float* sa_ob = (const float*)d_in[23];
    const float* ed_qw = (const float*)d_in[24]; const float* ed_qb = (const float*)d_in[25];
    const float* ed_kw = (const float*)d_in[26]; const float* ed_kb = (const float*)d_in[27];
    const float* ed_vw = (const float*)d_in[28]; const float* ed_vb = (const float*)d_in[29];
    const float* ed_ow = (const float*)d_in[30]; const float* ed_ob = (const float*)d_in[31];
    const float* ff_w1 = (const float*)d_in[32]; const float* ff_b1 = (const float*)d_in[33];
    const float* ff_w2 = (const float*)d_in[34]; const float* ff_b2 = (const float*)d_in[35];
    const float* ln1_g = (const float*)d_in[36]; const float* ln1_b = (const float*)d_in[37];
    const float* ln2_g = (const float*)d_in[38]; const float* ln2_b = (const float*)d_in[39];

    const int M = B_ * SD_;                 // 8192
    const size_t MM = (size_t)1024 * 1024;
    bf16* ws = (bf16*)d_ws;

    // ---- workspace layout (bf16 units) ----
    bf16* Wqkv = ws;                 // [3072,1024]
    bf16* Wkv  = ws + 3 * MM;        // [2048,1024]
    bf16* Wq2  = ws + 5 * MM;
    bf16* Wso  = ws + 6 * MM;
    bf16* Weo  = ws + 7 * MM;
    bf16* Wf1  = ws + 8 * MM;
    bf16* Wf2  = ws + 12 * MM;
    float* bQKV = (float*)(ws + 16 * MM);          // 3072 f
    float* bKV  = bQKV + 3072;                     // 2048 f
    float* bQ2  = bKV + 2048;                      // 1024 f
    float* Lsum = bQ2 + 2048;                      // 2*32*2048 f = 512 KB
    bf16* hw   = ws + 17 * MM;
    bf16* ft   = ws + 23 * MM;
    bf16* emb_b = ws + 17 * MM;      // 8M (aliases hw -- written AFTER gemm_prep)
    bf16* enc_b = ws + 25 * MM;      // 8M (aliases ft tail -- written AFTER gemm_prep)
    bf16* sqkv  = ws + 33 * MM;      // 24M [8192,3072]
    bf16* skv   = ws + 33 * MM;      // 16M [8192,2048] (after flash1)
    bf16* sq2   = ws + 49 * MM;      // 8M
    bf16* sVt   = ws + 57 * MM;      // 8M  [32][128][2048]
    bf16* attn  = ws + 65 * MM;      // 8M
    bf16* Ofb   = ws + 73 * MM;      // 16M (2 splits x 8M, unnormalized O)
    bf16* s1    = ws + 73 * MM;      // 8M (reused after combine)
    bf16* x     = ws + 89 * MM;      // 8M
    bf16* y     = ws + 33 * MM;      // 8M (after flash2)
    bf16* mid   = ws + 41 * MM;      // 32M
    bf16* f2    = ws + 81 * MM;      // 8M

    auto G = [&](const bf16* Ai, const bf16* Wi, const float* bi, bf16* Ci,
                 int Mi, int Ni, int Ki, bool relu) {
        dim3 grid(Ni / 128, Mi / 256);
        if (relu) gemm256<1><<<grid, 512, 0, stream>>>(Ai, Wi, bi, Ci, Mi, Ni, Ki);
        else      gemm256<0><<<grid, 512, 0, stream>>>(Ai, Wi, bi, Ci, Mi, Ni, Ki);
    };

    // ---- weight preparation (batched; ORDER MATTERS: gemm_prep must consume
    //      hw/ft BEFORE the misc convert overwrites them via emb_b/enc_b) ----
    {   // 6 per-head weight converts -> hw
        PtrsIn in; PtrsOut out; Int6 n;
        const float* s6[6] = {sa_qw, sa_kw, sa_vw, ed_qw, ed_kw, ed_vw};
        for (int i = 0; i < 6; ++i) { in.p[i] = s6[i]; out.p[i] = hw + i * MM; n.v[i] = (int)MM; }
        cvt6<<<dim3(512, 6), 256, 0, stream>>>(in, out, n);
    }
    {   // 6 transposed linear-weight converts -> ft
        PtrsIn in;
        const float* s6[6] = {q1_w, k1_w, v1_w, q2_w, k2_w, v2_w};
        for (int i = 0; i < 6; ++i) in.p[i] = s6[i];
        cvtT6<<<dim3(32, 32, 6), 256, 0, stream>>>(in, ft);
    }
    {   // 6 weight-compose GEMMs (one launch, 384 blocks) -- reads hw+ft
        PtrsIn A, W; PtrsOut C;
        const int idx[6] = {0, 1, 2, 4, 5, 3};
        bf16* c6[6] = {Wqkv, Wqkv + MM, Wqkv + 2 * MM, Wkv, Wkv + MM, Wq2};
        for (int i = 0; i < 6; ++i) {
            A.p[i] = hw + (size_t)idx[i] * MM;
            W.p[i] = ft + (size_t)idx[i] * MM;
            C.p[i] = c6[i];
        }
        gemm_prep<<<dim3(8, 8, 6), 256, 0, stream>>>(A, W, C);
    }
    {   // 6 composed biases (reads original f32 inputs only)
        PtrsIn w, bi, ba; PtrsOut o;
        const float* w6[6]  = {sa_qw, sa_kw, sa_vw, ed_kw, ed_vw, ed_qw};
        const float* bi6[6] = {q1_b, k1_b, v1_b, k2_b, v2_b, q2_b};
        const float* ba6[6] = {sa_qb, sa_kb, sa_vb, ed_kb, ed_vb, ed_qb};
        float* o6[6] = {bQKV, bQKV + 1024, bQKV + 2048, bKV, bKV + 1024, bQ2};
        for (int i = 0; i < 6; ++i) { w.p[i] = w6[i]; bi.p[i] = bi6[i]; ba.p[i] = ba6[i]; o.p[i] = o6[i]; }
        bias6<<<dim3(1024, 6), 256, 0, stream>>>(w, bi, ba, o);
    }
    {   // misc converts: proj/FFN weights + activations (overwrites hw/ft region)
        PtrsIn in; PtrsOut out; Int6 n;
        const float* s6[6] = {sa_ow, ed_ow, ff_w1, ff_w2, emb, enc};
        void* d6[6] = {Wso, Weo, Wf1, Wf2, emb_b, enc_b};
        int n6[6] = {(int)MM, (int)MM, (int)(4 * MM), (int)(4 * MM), (int)(8 * MM), (int)(8 * MM)};
        for (int i = 0; i < 6; ++i) { in.p[i] = s6[i]; out.p[i] = d6[i]; n.v[i] = n6[i]; }
        cvt6<<<dim3(4096, 6), 256, 0, stream>>>(in, out, n);
    }

    // ---- self attention ----
    G(emb_b, Wqkv, bQKV, sqkv, M, 3072, DM_, false);          // Qh|Kh|Vh
    vtrans<<<dim3(SD_ / 32, 4, B_ * H_), 256, 0, stream>>>(sqkv + 2048, 3072, sVt, SD_);
    flash_attn<1><<<dim3(B_ * H_, 2, SD_ / 256), 256, 0, stream>>>(
        sqkv, 3072, sqkv + 1024, 3072, sVt, out_pad, Ofb, Lsum, SD_, SD_);
    attn_combine<<<dim3(M), 256, 0, stream>>>(Ofb, Lsum, attn);
    G(attn, Wso, sa_ob, s1, M, DM_, DM_, false);
    add_ln<1, 0><<<dim3(M), 256, 0, stream>>>(emb, s1, ln1_g, ln1_b, x);

    // ---- cross attention (residual from emb, per reference) ----
    G(enc_b, Wkv, bKV, skv, M, 2048, DM_, false);             // Kh2|Vh2
    G(x, Wq2, bQ2, sq2, M, DM_, DM_, false);                  // Qh2
    vtrans<<<dim3(SE_ / 32, 4, B_ * H_), 256, 0, stream>>>(skv + 1024, 2048, sVt, SE_);
    flash_attn<0><<<dim3(B_ * H_, 2, SD_ / 128), 256, 0, stream>>>(
        sq2, 1024, skv, 2048, sVt, in_pad, Ofb, Lsum, SD_, SE_);
    attn_combine<<<dim3(M), 256, 0, stream>>>(Ofb, Lsum, attn);
    G(attn, Weo, ed_ob, s1, M, DM_, DM_, false);
    add_ln<1, 0><<<dim3(M), 256, 0, stream>>>(emb, s1, ln2_g, ln2_b, y);

    // ---- FFN (final norm reuses ln2 params, per reference) ----
    G(y, Wf1, ff_b1, mid, M, DFF_, DM_, true);
    G(mid, Wf2, ff_b2, f2, M, DM_, DFF_, false);
    add_ln<0, 1><<<dim3(M), 256, 0, stream>>>(y, f2, ln2_g, ln2_b, d_out);
}